// Round 9
// baseline (245.934 us; speedup 1.0000x reference)
//
#include <hip/hip_runtime.h>
#include <cstdint>
#include <cstddef>

#define Bv 4
#define Sv 2048
#define Hv 16
#define Dv 1024
#define Mv (Bv*Sv)   // 8192

typedef __attribute__((ext_vector_type(8))) short short8;
typedef __attribute__((ext_vector_type(8))) unsigned short ushort8v;
typedef __attribute__((ext_vector_type(4))) float f32x4;

__device__ inline float bf2f(unsigned short u) {
  union { unsigned int i; float f; } x; x.i = ((unsigned int)u) << 16; return x.f;
}
__device__ inline unsigned short f2bf(float f) {
  union { float f; unsigned int i; } x; x.f = f;
  unsigned int r = x.i + 0x7FFFu + ((x.i >> 16) & 1u);
  return (unsigned short)(r >> 16);
}

typedef __attribute__((address_space(1))) const unsigned short gu16;
typedef __attribute__((address_space(3))) unsigned short lu16;
__device__ inline void gld_lds16(const unsigned short* g, unsigned short* l) {
  __builtin_amdgcn_global_load_lds((gu16*)g, (lu16*)l, 16, 0, 0);
}

// ---------------- fp32 -> bf16 convert ----------------
__global__ __launch_bounds__(256) void cvt_f32_bf16(const float* __restrict__ src,
                                                    unsigned short* __restrict__ dst, int n4) {
  int i = blockIdx.x * 256 + threadIdx.x;
  if (i >= n4) return;
  float4 v = reinterpret_cast<const float4*>(src)[i];
  ushort4 o;
  o.x = f2bf(v.x); o.y = f2bf(v.y); o.z = f2bf(v.z); o.w = f2bf(v.w);
  reinterpret_cast<ushort4*>(dst)[i] = o;
}

// three weights -> one contiguous [3072][1024] bf16 buffer
__global__ __launch_bounds__(256) void cvt3_f32_bf16(const float* __restrict__ s0,
                                                     const float* __restrict__ s1,
                                                     const float* __restrict__ s2,
                                                     unsigned short* __restrict__ dst) {
  int i = blockIdx.x * 256 + threadIdx.x;   // 3*262144 float4 units
  int w = i >> 18, off = i & 262143;
  const float* src = (w == 0) ? s0 : (w == 1) ? s1 : s2;
  float4 v = reinterpret_cast<const float4*>(src)[off];
  ushort4 o;
  o.x = f2bf(v.x); o.y = f2bf(v.y); o.z = f2bf(v.z); o.w = f2bf(v.w);
  reinterpret_cast<ushort4*>(dst)[i] = o;
}

// ---------------- RoPE cos/sin table: tab[s][0:32]=cos, tab[s][32:64]=sin ----------------
__global__ __launch_bounds__(256) void rope_table_k(const int* __restrict__ pos,
                                                    float* __restrict__ tab) {
  int idx = blockIdx.x * 256 + threadIdx.x;  // Sv*32
  int s = idx >> 5, i = idx & 31;
  float p = (float)pos[s];
  float a = p * __builtin_exp2f(-0.41524101186092027f * (float)i);
  tab[(s << 6) + i]      = __builtin_cosf(a);
  tab[(s << 6) + 32 + i] = __builtin_sinf(a);
}

// bijective XCD-chunk swizzle (T1, m204): valid when nwg % 8 == 0
__device__ __forceinline__ void xcd_swizzle(int& bm, int& bn) {
  const int nx = gridDim.x;
  const int nwg = nx * gridDim.y;
  int flat = blockIdx.y * nx + blockIdx.x;
  if ((nwg & 7) == 0) {
    int q = nwg >> 3;
    flat = (flat & 7) * q + (flat >> 3);
  }
  bm = (flat / nx) * 128;
  bn = (flat % nx) * 128;
}

// ---------------- bf16 GEMM core (m97): C = A[M,K] * B[N,K]^T ------------
__device__ inline void storeC(float* p, float v) { *p = v; }
__device__ inline void storeC(unsigned short* p, float v) { *p = f2bf(v); }

template <typename CT>
__global__ __launch_bounds__(256) void gemm_bt_128(
    const unsigned short* __restrict__ A,
    const unsigned short* __restrict__ B,
    CT* __restrict__ C,
    int M, int N, int K) {
  __shared__ unsigned short As[128 * 32];
  __shared__ unsigned short Bs[128 * 32];
  const int tid = threadIdx.x;
  const int wave = tid >> 6, lane = tid & 63;
  int bm, bn;
  xcd_swizzle(bm, bn);
  const int wr = (wave >> 1) * 64, wc = (wave & 1) * 64;

  f32x4 acc[4][4] = {};

  const int c0 = wave * 2, c1 = c0 + 1;
  const int sr0 = c0 * 16 + (lane >> 2);
  const int sr1 = c1 * 16 + (lane >> 2);
  const int scol = (lane & 3) * 8;

  const unsigned short* gA0 = A + (size_t)(bm + sr0) * K + scol;
  const unsigned short* gA1 = A + (size_t)(bm + sr1) * K + scol;
  const unsigned short* gB0 = B + (size_t)(bn + sr0) * K + scol;
  const unsigned short* gB1 = B + (size_t)(bn + sr1) * K + scol;
  unsigned short* lA0 = &As[c0 * 512];
  unsigned short* lA1 = &As[c1 * 512];
  unsigned short* lB0 = &Bs[c0 * 512];
  unsigned short* lB1 = &Bs[c1 * 512];

  const int fr = lane & 15;
  const int fk = (lane >> 4) * 8;

  for (int k0 = 0; k0 < K; k0 += 32) {
    gld_lds16(gA0 + k0, lA0);
    gld_lds16(gA1 + k0, lA1);
    gld_lds16(gB0 + k0, lB0);
    gld_lds16(gB1 + k0, lB1);
    __syncthreads();
    short8 af[4], bfr[4];
#pragma unroll
    for (int m = 0; m < 4; m++)
      af[m] = *reinterpret_cast<const short8*>(&As[(wr + m * 16 + fr) * 32 + fk]);
#pragma unroll
    for (int n = 0; n < 4; n++)
      bfr[n] = *reinterpret_cast<const short8*>(&Bs[(wc + n * 16 + fr) * 32 + fk]);
#pragma unroll
    for (int m = 0; m < 4; m++)
#pragma unroll
      for (int n = 0; n < 4; n++)
        acc[m][n] = __builtin_amdgcn_mfma_f32_16x16x32_bf16(af[m], bfr[n], acc[m][n], 0, 0, 0);
    __syncthreads();
  }

  const int er = (lane >> 4) * 4, ec = lane & 15;
#pragma unroll
  for (int m = 0; m < 4; m++)
#pragma unroll
    for (int n = 0; n < 4; n++)
#pragma unroll
      for (int r = 0; r < 4; r++) {
        int row = bm + wr + m * 16 + er + r;
        int col = bn + wc + n * 16 + ec;
        storeC(&C[(size_t)row * N + col], acc[m][n][r]);
      }
}

// ---------------- fused QKV GEMM: N=3072, epilogue does RoPE (Q,K) / transpose (V) -------
__global__ __launch_bounds__(256) void gemm_qkv(
    const unsigned short* __restrict__ A,
    const unsigned short* __restrict__ B,
    unsigned short* __restrict__ Qp,
    unsigned short* __restrict__ Kp,
    unsigned short* __restrict__ Vt,
    const float* __restrict__ tab) {
  const int K = Dv;
  __shared__ unsigned short As[128 * 32];
  __shared__ unsigned short Bs[128 * 32];
  const int tid = threadIdx.x;
  const int wave = tid >> 6, lane = tid & 63;
  int bm, bn;
  xcd_swizzle(bm, bn);
  const int wr = (wave >> 1) * 64, wc = (wave & 1) * 64;

  f32x4 acc[4][4] = {};

  const int c0 = wave * 2, c1 = c0 + 1;
  const int sr0 = c0 * 16 + (lane >> 2);
  const int sr1 = c1 * 16 + (lane >> 2);
  const int scol = (lane & 3) * 8;

  const unsigned short* gA0 = A + (size_t)(bm + sr0) * K + scol;
  const unsigned short* gA1 = A + (size_t)(bm + sr1) * K + scol;
  const unsigned short* gB0 = B + (size_t)(bn + sr0) * K + scol;
  const unsigned short* gB1 = B + (size_t)(bn + sr1) * K + scol;
  unsigned short* lA0 = &As[c0 * 512];
  unsigned short* lA1 = &As[c1 * 512];
  unsigned short* lB0 = &Bs[c0 * 512];
  unsigned short* lB1 = &Bs[c1 * 512];

  const int fr = lane & 15;
  const int fk = (lane >> 4) * 8;

  for (int k0 = 0; k0 < K; k0 += 32) {
    gld_lds16(gA0 + k0, lA0);
    gld_lds16(gA1 + k0, lA1);
    gld_lds16(gB0 + k0, lB0);
    gld_lds16(gB1 + k0, lB1);
    __syncthreads();
    short8 af[4], bfr[4];
#pragma unroll
    for (int m = 0; m < 4; m++)
      af[m] = *reinterpret_cast<const short8*>(&As[(wr + m * 16 + fr) * 32 + fk]);
#pragma unroll
    for (int n = 0; n < 4; n++)
      bfr[n] = *reinterpret_cast<const short8*>(&Bs[(wc + n * 16 + fr) * 32 + fk]);
#pragma unroll
    for (int m = 0; m < 4; m++)
#pragma unroll
      for (int n = 0; n < 4; n++)
        acc[m][n] = __builtin_amdgcn_mfma_f32_16x16x32_bf16(af[m], bfr[n], acc[m][n], 0, 0, 0);
    __syncthreads();
  }

  const int er = (lane >> 4) * 4, ec = lane & 15;
  const int region = bn >> 10;  // block-uniform: 0=Q, 1=K, 2=V
  if (region < 2) {
    unsigned short* T = (region == 0) ? Qp : Kp;
#pragma unroll
    for (int m = 0; m < 4; m++)
#pragma unroll
      for (int n = 0; n < 4; n++) {
        const int col = bn + wc + n * 16 + ec;
        const int ccol = col & (Dv - 1);
        const int ii = (ccol & 63) >> 1;
        const bool odd = col & 1;
#pragma unroll
        for (int r = 0; r < 4; r++) {
          int row = bm + wr + m * 16 + er + r;
          int s = row & (Sv - 1);
          float v = acc[m][n][r];
          float pv = __shfl_xor(v, 1);  // paired feature lives in lane^1 (ec^1)
          float cc = tab[(s << 6) + ii];
          float sn = tab[(s << 6) + 32 + ii];
          float o = odd ? __builtin_fmaf(pv, sn, v * cc)
                        : __builtin_fmaf(v, cc, -(pv * sn));
          T[(size_t)row * Dv + ccol] = f2bf(o);
        }
      }
  } else {
#pragma unroll
    for (int m = 0; m < 4; m++)
#pragma unroll
      for (int n = 0; n < 4; n++) {
        const int dfull = (bn - 2048) + wc + n * 16 + ec;  // h*64+d
        const int row0 = bm + wr + m * 16 + er;            // 4 consecutive rows (same b)
        const int bb = row0 >> 11, s = row0 & (Sv - 1);
        const size_t vtrow = ((size_t)bb * 16 + (dfull >> 6)) * 64 + (dfull & 63);
        ushort4 ov;
        ov.x = f2bf(acc[m][n][0]);
        ov.y = f2bf(acc[m][n][1]);
        ov.z = f2bf(acc[m][n][2]);
        ov.w = f2bf(acc[m][n][3]);
        *reinterpret_cast<ushort4*>(Vt + vtrow * Sv + s) = ov;
      }
  }
}

// ---------------- MFMA flash attention helpers (32-row strips) ----------------
// S^T layout per strip: lane (g=lane>>4, m=lane&15) holds S^T[k=16*kf+4g+r][q=qf*16+m].
__device__ __forceinline__ void softmax_strip(
    f32x4 (&sacc)[2][4], const bool lastt, const int qrel0,
    float (&mrun2)[2], float (&lrun)[2], f32x4 (&oacc)[2][4],
    unsigned int (&pk)[2][4][2]) {
  const float c1 = 0.18033688011112042f;  // log2(e)/8  (scale = 1/sqrt(64))
#pragma unroll
  for (int qf = 0; qf < 2; ++qf) {
    const int qrel = qrel0 + qf * 16;
    float pv[4][4];
    float mx = -INFINITY;
#pragma unroll
    for (int kf = 0; kf < 4; ++kf)
#pragma unroll
      for (int r = 0; r < 4; ++r) {
        float s = sacc[qf][kf][r];
        if (lastt) s = (kf * 16 + r > qrel) ? -INFINITY : s;
        pv[kf][r] = s;
        mx = fmaxf(mx, s);
      }
    mx = fmaxf(mx, __shfl_xor(mx, 16));
    mx = fmaxf(mx, __shfl_xor(mx, 32));
    float pm = mx * c1;
    if (__any(pm > mrun2[qf] + 8.0f)) {  // defer-max (T13)
      float m2 = fmaxf(mrun2[qf], pm);
      float sfq = __builtin_exp2f(mrun2[qf] - m2);
      lrun[qf] *= sfq;
#pragma unroll
      for (int dc = 0; dc < 4; ++dc)
#pragma unroll
        for (int r = 0; r < 4; ++r) oacc[qf][dc][r] *= sfq;
      mrun2[qf] = m2;
    }
    const float nm = -mrun2[qf];
    float ps = 0.f;
#pragma unroll
    for (int kf = 0; kf < 4; ++kf)
#pragma unroll
      for (int r = 0; r < 4; ++r) {
        float p = __builtin_exp2f(__builtin_fmaf(pv[kf][r], c1, nm));
        ps += p;
        pv[kf][r] = p;
      }
    ps += __shfl_xor(ps, 16);
    ps += __shfl_xor(ps, 32);
    lrun[qf] += ps;
#pragma unroll
    for (int kf = 0; kf < 4; ++kf)
#pragma unroll
      for (int hh = 0; hh < 2; ++hh) {
        unsigned int rr;
        asm("v_cvt_pk_bf16_f32 %0, %1, %2"
            : "=v"(rr) : "v"(pv[kf][2 * hh]), "v"(pv[kf][2 * hh + 1]));
        pk[qf][kf][hh] = rr;
      }
  }
}

// P^T B-frags via ds_bpermute: word t of target (g',m) = pk[2ks+(g'>>1)][t&1]
// from source lane 16*(2(g'&1)+(t>>1)) + m.
__device__ __forceinline__ void pv_strip(
    const short8 (&vfr)[2][4], const unsigned int (&pk)[2][4][2],
    f32x4 (&oacc)[2][4], const int idx0, const int idx1, const bool hi) {
#pragma unroll
  for (int ks = 0; ks < 2; ++ks)
#pragma unroll
    for (int qf = 0; qf < 2; ++qf) {
      int ra = __builtin_amdgcn_ds_bpermute(idx0, (int)pk[qf][2 * ks][0]);
      int rb = __builtin_amdgcn_ds_bpermute(idx0, (int)pk[qf][2 * ks + 1][0]);
      int rc = __builtin_amdgcn_ds_bpermute(idx0, (int)pk[qf][2 * ks][1]);
      int rd = __builtin_amdgcn_ds_bpermute(idx0, (int)pk[qf][2 * ks + 1][1]);
      int re = __builtin_amdgcn_ds_bpermute(idx1, (int)pk[qf][2 * ks][0]);
      int rf = __builtin_amdgcn_ds_bpermute(idx1, (int)pk[qf][2 * ks + 1][0]);
      int rg = __builtin_amdgcn_ds_bpermute(idx1, (int)pk[qf][2 * ks][1]);
      int rh = __builtin_amdgcn_ds_bpermute(idx1, (int)pk[qf][2 * ks + 1][1]);
      union { unsigned int u[4]; short8 v; } pw;
      pw.u[0] = hi ? (unsigned)rb : (unsigned)ra;
      pw.u[1] = hi ? (unsigned)rd : (unsigned)rc;
      pw.u[2] = hi ? (unsigned)rf : (unsigned)re;
      pw.u[3] = hi ? (unsigned)rh : (unsigned)rg;
      __builtin_amdgcn_s_setprio(1);
#pragma unroll
      for (int dc = 0; dc < 4; ++dc)
        oacc[qf][dc] = __builtin_amdgcn_mfma_f32_16x16x32_bf16(vfr[ks][dc], pw.v, oacc[qf][dc], 0, 0, 0);
      __builtin_amdgcn_s_setprio(0);
    }
}

// ---------------- MFMA flash attention (causal), 32-row paired strips, split-k x2 ------
// Per (b,h): 32 strip-pairs (sA=j, sB=63-j). Each pair's k-tiles [0,ntB) split between
// 2 waves: wave half=0 takes [0,T0), half=1 takes [T0,ntB); partials merged in LDS via
// flash m/l/O rescale. No staging, no in-loop barriers: K/V read direct from global —
// L2-resident thanks to XCD-affine bh mapping (r8: FETCH 131->25MB). Grid 1024 blocks
// x 4 waves = 16 waves/CU (VGPR=128 allows 4/SIMD per m69).
__global__ __launch_bounds__(256, 2) void attn_mfma(
    const unsigned short* __restrict__ Q,
    const unsigned short* __restrict__ K,
    const unsigned short* __restrict__ Vt,
    unsigned short* __restrict__ O) {
  __shared__ float cbO[2][64][32];   // 16 KB: combine buffer (per wave-pair)
  __shared__ float cbML[2][64][4];   // 2 KB: m,l per qf
  const int tid = threadIdx.x;
  const int wave = tid >> 6, lane = tid & 63;
  const int g = lane >> 4, m = lane & 15;
  const int F = blockIdx.x;                  // 0..1023
  const int i6 = F >> 3;
  const int bh = ((F & 7) << 3) | (i6 & 7);  // XCD-affine (r8 mapping, 16 blocks/bh)
  const int gidx = i6 >> 3;                  // 0..15
  const int pi = wave >> 1, half = wave & 1;
  const int j = gidx * 2 + pi;               // pair 0..31
  const int sA = j, sB = 63 - j;
  const int qA0 = sA * 32, qB0 = sB * 32;
  const int ntA = (sA >> 1) + 1, ntB = (sB >> 1) + 1;  // ntA <= 16 < ntB <= 32
  const int T0 = (ntB + 1) >> 1;
  const int tBeg = half ? T0 : 0;
  const int tEnd = half ? ntB : T0;
  const int b = bh >> 4, h = bh & 15;
  const size_t qkbase = ((size_t)b * Sv) * Dv + (size_t)h * 64;
  const size_t vtbase = (size_t)bh * 64 * Sv;
  const f32x4 zf = {0.f, 0.f, 0.f, 0.f};

  short8 qA[2][2], qB[2][2];
#pragma unroll
  for (int qf = 0; qf < 2; ++qf)
#pragma unroll
    for (int ks = 0; ks < 2; ++ks) {
      qA[qf][ks] = *reinterpret_cast<const short8*>(
          Q + qkbase + (size_t)(qA0 + qf * 16 + m) * Dv + ks * 32 + g * 8);
      qB[qf][ks] = *reinterpret_cast<const short8*>(
          Q + qkbase + (size_t)(qB0 + qf * 16 + m) * Dv + ks * 32 + g * 8);
    }

  const unsigned short* kp[4];
  const unsigned short* vp[4];
#pragma unroll
  for (int kf = 0; kf < 4; ++kf)
    kp[kf] = K + qkbase + (size_t)(kf * 16 + m) * Dv + g * 8 + (size_t)tBeg * 64 * Dv;
#pragma unroll
  for (int dc = 0; dc < 4; ++dc)
    vp[dc] = Vt + vtbase + (size_t)(dc * 16 + m) * Sv + g * 8 + tBeg * 64;

  f32x4 oA[2][4] = {}, oB[2][4] = {};
  float mA[2] = {-INFINITY, -INFINITY}, mB[2] = {-INFINITY, -INFINITY};
  float lA[2] = {0.f, 0.f}, lB[2] = {0.f, 0.f};

  const int idx0 = (((g & 1) << 5) + m) << 2;
  const int idx1 = idx0 + 64;
  const bool hi = (g >= 2);
  int qrelA = qA0 + m - 4 * g - tBeg * 64;
  int qrelB = qB0 + m - 4 * g - tBeg * 64;

  for (int t = tBeg; t < tEnd; ++t) {
    const bool actA = (t < ntA);
    f32x4 sAacc[2][4], sBacc[2][4];
    short8 kfr[4];
#pragma unroll
    for (int kf = 0; kf < 4; ++kf)
      kfr[kf] = *reinterpret_cast<const short8*>(kp[kf]);
    __builtin_amdgcn_s_setprio(1);
#pragma unroll
    for (int qf = 0; qf < 2; ++qf)
#pragma unroll
      for (int kf = 0; kf < 4; ++kf)
        sBacc[qf][kf] = __builtin_amdgcn_mfma_f32_16x16x32_bf16(kfr[kf], qB[qf][0], zf, 0, 0, 0);
    if (actA)
#pragma unroll
      for (int qf = 0; qf < 2; ++qf)
#pragma unroll
        for (int kf = 0; kf < 4; ++kf)
          sAacc[qf][kf] = __builtin_amdgcn_mfma_f32_16x16x32_bf16(kfr[kf], qA[qf][0], zf, 0, 0, 0);
    __builtin_amdgcn_s_setprio(0);
#pragma unroll
    for (int kf = 0; kf < 4; ++kf)
      kfr[kf] = *reinterpret_cast<const short8*>(kp[kf] + 32);
    __builtin_amdgcn_s_setprio(1);
#pragma unroll
    for (int qf = 0; qf < 2; ++qf)
#pragma unroll
      for (int kf = 0; kf < 4; ++kf)
        sBacc[qf][kf] = __builtin_amdgcn_mfma_f32_16x16x32_bf16(kfr[kf], qB[qf][1], sBacc[qf][kf], 0, 0, 0);
    if (actA)
#pragma unroll
      for (int qf = 0; qf < 2; ++qf)
#pragma unroll
        for (int kf = 0; kf < 4; ++kf)
          sAacc[qf][kf] = __builtin_amdgcn_mfma_f32_16x16x32_bf16(kfr[kf], qA[qf][1], sAacc[qf][kf], 0, 0, 0);
    __builtin_amdgcn_s_setprio(0);

    short8 vfr[2][4];
#pragma unroll
    for (int ks = 0; ks < 2; ++ks)
#pragma unroll
      for (int dc = 0; dc < 4; ++dc)
        vfr[ks][dc] = *reinterpret_cast<const short8*>(vp[dc] + ks * 32);

    unsigned int pkB[2][4][2], pkA[2][4][2];
    softmax_strip(sBacc, t == ntB - 1, qrelB, mB, lB, oB, pkB);
    if (actA) softmax_strip(sAacc, t == ntA - 1, qrelA, mA, lA, oA, pkA);
    pv_strip(vfr, pkB, oB, idx0, idx1, hi);
    if (actA) pv_strip(vfr, pkA, oA, idx0, idx1, hi);

#pragma unroll
    for (int kf = 0; kf < 4; ++kf) kp[kf] += (size_t)64 * Dv;
#pragma unroll
    for (int dc = 0; dc < 4; ++dc) vp[dc] += 64;
    qrelA -= 64; qrelB -= 64;
  }

  // ---- split-k combine via LDS (phased per strip to bound LDS at 18 KB) ----
  // strip B
  if (half) {
#pragma unroll
    for (int qf = 0; qf < 2; ++qf) {
      cbML[pi][lane][qf * 2]     = mB[qf];
      cbML[pi][lane][qf * 2 + 1] = lB[qf];
#pragma unroll
      for (int dc = 0; dc < 4; ++dc)
#pragma unroll
        for (int r = 0; r < 4; ++r)
          cbO[pi][lane][qf * 16 + dc * 4 + r] = oB[qf][dc][r];
    }
  }
  __syncthreads();
  if (!half) {
#pragma unroll
    for (int qf = 0; qf < 2; ++qf) {
      float mH = cbML[pi][lane][qf * 2], lH = cbML[pi][lane][qf * 2 + 1];
      float m2 = fmaxf(mB[qf], mH);
      float sfL = __builtin_exp2f(mB[qf] - m2);
      float sfH = __builtin_exp2f(mH - m2);
      lB[qf] = lB[qf] * sfL + lH * sfH;
#pragma unroll
      for (int dc = 0; dc < 4; ++dc)
#pragma unroll
        for (int r = 0; r < 4; ++r)
          oB[qf][dc][r] = oB[qf][dc][r] * sfL + cbO[pi][lane][qf * 16 + dc * 4 + r] * sfH;
    }
  }
  __syncthreads();
  // strip A
  if (half) {
#pragma unroll
    for (int qf = 0; qf < 2; ++qf) {
      cbML[pi][lane][qf * 2]     = mA[qf];
      cbML[pi][lane][qf * 2 + 1] = lA[qf];
#pragma unroll
      for (int dc = 0; dc < 4; ++dc)
#pragma unroll
        for (int r = 0; r < 4; ++r)
          cbO[pi][lane][qf * 16 + dc * 4 + r] = oA[qf][dc][r];
    }
  }
  __syncthreads();
  if (!half) {
#pragma unroll
    for (int qf = 0; qf < 2; ++qf) {
      float mH = cbML[pi][lane][qf * 2], lH = cbML[pi][lane][qf * 2 + 1];
      float m2 = fmaxf(mA[qf], mH);
      float sfL = __builtin_exp2f(mA[qf] - m2);
      float sfH = __builtin_exp2f(mH - m2);
      lA[qf] = lA[qf] * sfL + lH * sfH;
#pragma unroll
      for (int dc = 0; dc < 4; ++dc)
#pragma unroll
        for (int r = 0; r < 4; ++r)
          oA[qf][dc][r] = oA[qf][dc][r] * sfL + cbO[pi][lane][qf * 16 + dc * 4 + r] * sfH;
    }

    // ---- store merged output (lo wave only) ----
#pragma unroll
    for (int qf = 0; qf < 2; ++qf) {
      float rnA = 1.0f / lA[qf];
      float rnB = 1.0f / lB[qf];
      size_t rowA = (size_t)(qA0 + qf * 16 + m);
      size_t rowB = (size_t)(qB0 + qf * 16 + m);
#pragma unroll
      for (int dc = 0; dc < 4; ++dc) {
        ushort4 ov;
        ov.x = f2bf(oA[qf][dc][0] * rnA);
        ov.y = f2bf(oA[qf][dc][1] * rnA);
        ov.z = f2bf(oA[qf][dc][2] * rnA);
        ov.w = f2bf(oA[qf][dc][3] * rnA);
        *reinterpret_cast<ushort4*>(O + qkbase + rowA * Dv + dc * 16 + 4 * g) = ov;
        ov.x = f2bf(oB[qf][dc][0] * rnB);
        ov.y = f2bf(oB[qf][dc][1] * rnB);
        ov.z = f2bf(oB[qf][dc][2] * rnB);
        ov.w = f2bf(oB[qf][dc][3] * rnB);
        *reinterpret_cast<ushort4*>(O + qkbase + rowB * Dv + dc * 16 + 4 * g) = ov;
      }
    }
  }
}

// ---------------- launcher ----------------
extern "C" void kernel_launch(void* const* d_in, const int* in_sizes, int n_in,
                              void* d_out, int out_size, void* d_ws, size_t ws_size,
                              hipStream_t stream) {
  const float* x   = (const float*)d_in[0];
  const int*   pos = (const int*)d_in[1];
  const float* wq  = (const float*)d_in[2];
  const float* wk  = (const float*)d_in[3];
  const float* wv  = (const float*)d_in[4];
  const float* wo  = (const float*)d_in[5];
  float* out = (float*)d_out;

  char* w = (char*)d_ws;
  unsigned short* xb    = (unsigned short*)(w);               // 16 MB: x bf16, later attn out
  unsigned short* wqkvb = (unsigned short*)(w + (16u << 20)); // 6 MB contiguous [3072][1024]
  unsigned short* wob   = (unsigned short*)(w + (22u << 20)); // 2 MB
  unsigned short* Qp    = (unsigned short*)(w + (24u << 20)); // 16 MB
  unsigned short* Kp    = (unsigned short*)(w + (40u << 20)); // 16 MB
  unsigned short* Vt    = (unsigned short*)(w + (56u << 20)); // 16 MB
  float*          tab   = (float*)(w + (72u << 20));          // 512 KB

  rope_table_k<<<(Sv * 32) / 256, 256, 0, stream>>>(pos, tab);
  cvt_f32_bf16<<<(Mv * Dv / 4) / 256, 256, 0, stream>>>(x, xb, Mv * Dv / 4);
  cvt3_f32_bf16<<<(3 * Dv * Dv / 4) / 256, 256, 0, stream>>>(wq, wk, wv, wqkvb);
  cvt_f32_bf16<<<(Dv * Dv / 4) / 256, 256, 0, stream>>>(wo, wob, Dv * Dv / 4);

  // fused QKV projection + RoPE + V-transpose
  gemm_qkv<<<dim3(3 * Dv / 128, Mv / 128), 256, 0, stream>>>(xb, wqkvb, Qp, Kp, Vt, tab);

  // attn out -> xb (x bf16 dead after gemm_qkv)
  attn_mfma<<<1024, 256, 0, stream>>>(Qp, Kp, Vt, xb);

  gemm_bt_128<float><<<dim3(Dv / 128, Mv / 128), 256, 0, stream>>>(xb, wob, out, Mv, Dv, Dv);
}

// Round 10
// 227.935 us; speedup vs baseline: 1.0790x; 1.0790x over previous
//
#include <hip/hip_runtime.h>
#include <cstdint>
#include <cstddef>

#define Bv 4
#define Sv 2048
#define Hv 16
#define Dv 1024
#define Mv (Bv*Sv)   // 8192

typedef __attribute__((ext_vector_type(8))) short short8;
typedef __attribute__((ext_vector_type(8))) unsigned short ushort8v;
typedef __attribute__((ext_vector_type(4))) float f32x4;

__device__ inline float bf2f(unsigned short u) {
  union { unsigned int i; float f; } x; x.i = ((unsigned int)u) << 16; return x.f;
}
__device__ inline unsigned short f2bf(float f) {
  union { float f; unsigned int i; } x; x.f = f;
  unsigned int r = x.i + 0x7FFFu + ((x.i >> 16) & 1u);
  return (unsigned short)(r >> 16);
}

typedef __attribute__((address_space(1))) const unsigned short gu16;
typedef __attribute__((address_space(3))) unsigned short lu16;
__device__ inline void gld_lds16(const unsigned short* g, unsigned short* l) {
  __builtin_amdgcn_global_load_lds((gu16*)g, (lu16*)l, 16, 0, 0);
}

// ---------------- fp32 -> bf16 convert ----------------
__global__ __launch_bounds__(256) void cvt_f32_bf16(const float* __restrict__ src,
                                                    unsigned short* __restrict__ dst, int n4) {
  int i = blockIdx.x * 256 + threadIdx.x;
  if (i >= n4) return;
  float4 v = reinterpret_cast<const float4*>(src)[i];
  ushort4 o;
  o.x = f2bf(v.x); o.y = f2bf(v.y); o.z = f2bf(v.z); o.w = f2bf(v.w);
  reinterpret_cast<ushort4*>(dst)[i] = o;
}

// three weights -> one contiguous [3072][1024] bf16 buffer
__global__ __launch_bounds__(256) void cvt3_f32_bf16(const float* __restrict__ s0,
                                                     const float* __restrict__ s1,
                                                     const float* __restrict__ s2,
                                                     unsigned short* __restrict__ dst) {
  int i = blockIdx.x * 256 + threadIdx.x;   // 3*262144 float4 units
  int w = i >> 18, off = i & 262143;
  const float* src = (w == 0) ? s0 : (w == 1) ? s1 : s2;
  float4 v = reinterpret_cast<const float4*>(src)[off];
  ushort4 o;
  o.x = f2bf(v.x); o.y = f2bf(v.y); o.z = f2bf(v.z); o.w = f2bf(v.w);
  reinterpret_cast<ushort4*>(dst)[i] = o;
}

// ---------------- RoPE cos/sin table: tab[s][0:32]=cos, tab[s][32:64]=sin ----------------
__global__ __launch_bounds__(256) void rope_table_k(const int* __restrict__ pos,
                                                    float* __restrict__ tab) {
  int idx = blockIdx.x * 256 + threadIdx.x;  // Sv*32
  int s = idx >> 5, i = idx & 31;
  float p = (float)pos[s];
  float a = p * __builtin_exp2f(-0.41524101186092027f * (float)i);
  tab[(s << 6) + i]      = __builtin_cosf(a);
  tab[(s << 6) + 32 + i] = __builtin_sinf(a);
}

// bijective XCD-chunk swizzle (T1, m204): valid when nwg % 8 == 0
__device__ __forceinline__ void xcd_swizzle(int& bm, int& bn) {
  const int nx = gridDim.x;
  const int nwg = nx * gridDim.y;
  int flat = blockIdx.y * nx + blockIdx.x;
  if ((nwg & 7) == 0) {
    int q = nwg >> 3;
    flat = (flat & 7) * q + (flat >> 3);
  }
  bm = (flat / nx) * 128;
  bn = (flat % nx) * 128;
}

// ---------------- bf16 GEMM core (m97): C = A[M,K] * B[N,K]^T ------------
__device__ inline void storeC(float* p, float v) { *p = v; }
__device__ inline void storeC(unsigned short* p, float v) { *p = f2bf(v); }

template <typename CT>
__global__ __launch_bounds__(256) void gemm_bt_128(
    const unsigned short* __restrict__ A,
    const unsigned short* __restrict__ B,
    CT* __restrict__ C,
    int M, int N, int K) {
  __shared__ unsigned short As[128 * 32];
  __shared__ unsigned short Bs[128 * 32];
  const int tid = threadIdx.x;
  const int wave = tid >> 6, lane = tid & 63;
  int bm, bn;
  xcd_swizzle(bm, bn);
  const int wr = (wave >> 1) * 64, wc = (wave & 1) * 64;

  f32x4 acc[4][4] = {};

  const int c0 = wave * 2, c1 = c0 + 1;
  const int sr0 = c0 * 16 + (lane >> 2);
  const int sr1 = c1 * 16 + (lane >> 2);
  const int scol = (lane & 3) * 8;

  const unsigned short* gA0 = A + (size_t)(bm + sr0) * K + scol;
  const unsigned short* gA1 = A + (size_t)(bm + sr1) * K + scol;
  const unsigned short* gB0 = B + (size_t)(bn + sr0) * K + scol;
  const unsigned short* gB1 = B + (size_t)(bn + sr1) * K + scol;
  unsigned short* lA0 = &As[c0 * 512];
  unsigned short* lA1 = &As[c1 * 512];
  unsigned short* lB0 = &Bs[c0 * 512];
  unsigned short* lB1 = &Bs[c1 * 512];

  const int fr = lane & 15;
  const int fk = (lane >> 4) * 8;

  for (int k0 = 0; k0 < K; k0 += 32) {
    gld_lds16(gA0 + k0, lA0);
    gld_lds16(gA1 + k0, lA1);
    gld_lds16(gB0 + k0, lB0);
    gld_lds16(gB1 + k0, lB1);
    __syncthreads();
    short8 af[4], bfr[4];
#pragma unroll
    for (int m = 0; m < 4; m++)
      af[m] = *reinterpret_cast<const short8*>(&As[(wr + m * 16 + fr) * 32 + fk]);
#pragma unroll
    for (int n = 0; n < 4; n++)
      bfr[n] = *reinterpret_cast<const short8*>(&Bs[(wc + n * 16 + fr) * 32 + fk]);
#pragma unroll
    for (int m = 0; m < 4; m++)
#pragma unroll
      for (int n = 0; n < 4; n++)
        acc[m][n] = __builtin_amdgcn_mfma_f32_16x16x32_bf16(af[m], bfr[n], acc[m][n], 0, 0, 0);
    __syncthreads();
  }

  const int er = (lane >> 4) * 4, ec = lane & 15;
#pragma unroll
  for (int m = 0; m < 4; m++)
#pragma unroll
    for (int n = 0; n < 4; n++)
#pragma unroll
      for (int r = 0; r < 4; r++) {
        int row = bm + wr + m * 16 + er + r;
        int col = bn + wc + n * 16 + ec;
        storeC(&C[(size_t)row * N + col], acc[m][n][r]);
      }
}

// ---------------- fused QKV GEMM: N=3072, epilogue does RoPE (Q,K) / transpose (V) -------
__global__ __launch_bounds__(256) void gemm_qkv(
    const unsigned short* __restrict__ A,
    const unsigned short* __restrict__ B,
    unsigned short* __restrict__ Qp,
    unsigned short* __restrict__ Kp,
    unsigned short* __restrict__ Vt,
    const float* __restrict__ tab) {
  const int K = Dv;
  __shared__ unsigned short As[128 * 32];
  __shared__ unsigned short Bs[128 * 32];
  const int tid = threadIdx.x;
  const int wave = tid >> 6, lane = tid & 63;
  int bm, bn;
  xcd_swizzle(bm, bn);
  const int wr = (wave >> 1) * 64, wc = (wave & 1) * 64;

  f32x4 acc[4][4] = {};

  const int c0 = wave * 2, c1 = c0 + 1;
  const int sr0 = c0 * 16 + (lane >> 2);
  const int sr1 = c1 * 16 + (lane >> 2);
  const int scol = (lane & 3) * 8;

  const unsigned short* gA0 = A + (size_t)(bm + sr0) * K + scol;
  const unsigned short* gA1 = A + (size_t)(bm + sr1) * K + scol;
  const unsigned short* gB0 = B + (size_t)(bn + sr0) * K + scol;
  const unsigned short* gB1 = B + (size_t)(bn + sr1) * K + scol;
  unsigned short* lA0 = &As[c0 * 512];
  unsigned short* lA1 = &As[c1 * 512];
  unsigned short* lB0 = &Bs[c0 * 512];
  unsigned short* lB1 = &Bs[c1 * 512];

  const int fr = lane & 15;
  const int fk = (lane >> 4) * 8;

  for (int k0 = 0; k0 < K; k0 += 32) {
    gld_lds16(gA0 + k0, lA0);
    gld_lds16(gA1 + k0, lA1);
    gld_lds16(gB0 + k0, lB0);
    gld_lds16(gB1 + k0, lB1);
    __syncthreads();
    short8 af[4], bfr[4];
#pragma unroll
    for (int m = 0; m < 4; m++)
      af[m] = *reinterpret_cast<const short8*>(&As[(wr + m * 16 + fr) * 32 + fk]);
#pragma unroll
    for (int n = 0; n < 4; n++)
      bfr[n] = *reinterpret_cast<const short8*>(&Bs[(wc + n * 16 + fr) * 32 + fk]);
#pragma unroll
    for (int m = 0; m < 4; m++)
#pragma unroll
      for (int n = 0; n < 4; n++)
        acc[m][n] = __builtin_amdgcn_mfma_f32_16x16x32_bf16(af[m], bfr[n], acc[m][n], 0, 0, 0);
    __syncthreads();
  }

  const int er = (lane >> 4) * 4, ec = lane & 15;
  const int region = bn >> 10;  // block-uniform: 0=Q, 1=K, 2=V
  if (region < 2) {
    unsigned short* T = (region == 0) ? Qp : Kp;
#pragma unroll
    for (int m = 0; m < 4; m++)
#pragma unroll
      for (int n = 0; n < 4; n++) {
        const int col = bn + wc + n * 16 + ec;
        const int ccol = col & (Dv - 1);
        const int ii = (ccol & 63) >> 1;
        const bool odd = col & 1;
#pragma unroll
        for (int r = 0; r < 4; r++) {
          int row = bm + wr + m * 16 + er + r;
          int s = row & (Sv - 1);
          float v = acc[m][n][r];
          float pv = __shfl_xor(v, 1);  // paired feature lives in lane^1 (ec^1)
          float cc = tab[(s << 6) + ii];
          float sn = tab[(s << 6) + 32 + ii];
          float o = odd ? __builtin_fmaf(pv, sn, v * cc)
                        : __builtin_fmaf(v, cc, -(pv * sn));
          T[(size_t)row * Dv + ccol] = f2bf(o);
        }
      }
  } else {
#pragma unroll
    for (int m = 0; m < 4; m++)
#pragma unroll
      for (int n = 0; n < 4; n++) {
        const int dfull = (bn - 2048) + wc + n * 16 + ec;  // h*64+d
        const int row0 = bm + wr + m * 16 + er;            // 4 consecutive rows (same b)
        const int bb = row0 >> 11, s = row0 & (Sv - 1);
        const size_t vtrow = ((size_t)bb * 16 + (dfull >> 6)) * 64 + (dfull & 63);
        ushort4 ov;
        ov.x = f2bf(acc[m][n][0]);
        ov.y = f2bf(acc[m][n][1]);
        ov.z = f2bf(acc[m][n][2]);
        ov.w = f2bf(acc[m][n][3]);
        *reinterpret_cast<ushort4*>(Vt + vtrow * Sv + s) = ov;
      }
  }
}

// ---------------- MFMA flash attention helpers (32-row strips) ----------------
// S^T layout per strip: lane (g=lane>>4, m=lane&15) holds S^T[k=16*kf+4g+r][q=qf*16+m].
// Tree-reduced max/sum (no -ffast-math: compiler can't reassociate serial chains) +
// 3-parallel-shfl coset reduce (v, v^16, v^32, v^48 covers all 4 lane groups).
__device__ __forceinline__ void softmax_strip(
    f32x4 (&sacc)[2][4], const bool lastt, const int qrel0,
    float (&mrun2)[2], float (&lrun)[2], f32x4 (&oacc)[2][4],
    unsigned int (&pk)[2][4][2]) {
  const float c1 = 0.18033688011112042f;  // log2(e)/8  (scale = 1/sqrt(64))
#pragma unroll
  for (int qf = 0; qf < 2; ++qf) {
    const int qrel = qrel0 + qf * 16;
    float pv[4][4];
#pragma unroll
    for (int kf = 0; kf < 4; ++kf)
#pragma unroll
      for (int r = 0; r < 4; ++r) {
        float s = sacc[qf][kf][r];
        if (lastt) s = (kf * 16 + r > qrel) ? -INFINITY : s;
        pv[kf][r] = s;
      }
    // in-lane tree max (depth 4)
    float xr[4];
#pragma unroll
    for (int r = 0; r < 4; ++r)
      xr[r] = fmaxf(fmaxf(pv[0][r], pv[1][r]), fmaxf(pv[2][r], pv[3][r]));
    float mx = fmaxf(fmaxf(xr[0], xr[1]), fmaxf(xr[2], xr[3]));
    // cross-lane coset max: 3 independent shfls
    float ma = __shfl_xor(mx, 16), mb = __shfl_xor(mx, 32), mc = __shfl_xor(mx, 48);
    mx = fmaxf(fmaxf(mx, ma), fmaxf(mb, mc));
    float pm = mx * c1;
    if (__any(pm > mrun2[qf] + 8.0f)) {  // defer-max (T13)
      float m2 = fmaxf(mrun2[qf], pm);
      float sfq = __builtin_exp2f(mrun2[qf] - m2);
      lrun[qf] *= sfq;
#pragma unroll
      for (int dc = 0; dc < 4; ++dc)
#pragma unroll
        for (int r = 0; r < 4; ++r) oacc[qf][dc][r] *= sfq;
      mrun2[qf] = m2;
    }
    const float nm = -mrun2[qf];
#pragma unroll
    for (int kf = 0; kf < 4; ++kf)
#pragma unroll
      for (int r = 0; r < 4; ++r)
        pv[kf][r] = __builtin_exp2f(__builtin_fmaf(pv[kf][r], c1, nm));
    // in-lane tree sum (depth 4)
    float sr[4];
#pragma unroll
    for (int r = 0; r < 4; ++r)
      sr[r] = (pv[0][r] + pv[1][r]) + (pv[2][r] + pv[3][r]);
    float ps = (sr[0] + sr[1]) + (sr[2] + sr[3]);
    // cross-lane coset sum: 3 independent shfls
    float sa = __shfl_xor(ps, 16), sb = __shfl_xor(ps, 32), sc = __shfl_xor(ps, 48);
    ps = (ps + sa) + (sb + sc);
    lrun[qf] += ps;
#pragma unroll
    for (int kf = 0; kf < 4; ++kf)
#pragma unroll
      for (int hh = 0; hh < 2; ++hh) {
        unsigned int rr;
        asm("v_cvt_pk_bf16_f32 %0, %1, %2"
            : "=v"(rr) : "v"(pv[kf][2 * hh]), "v"(pv[kf][2 * hh + 1]));
        pk[qf][kf][hh] = rr;
      }
  }
}

// P^T B-frags via ds_bpermute: word t of target (g',m) = pk[2ks+(g'>>1)][t&1]
// from source lane 16*(2(g'&1)+(t>>1)) + m.
__device__ __forceinline__ void pv_strip(
    const short8 (&vfr)[2][4], const unsigned int (&pk)[2][4][2],
    f32x4 (&oacc)[2][4], const int idx0, const int idx1, const bool hi) {
#pragma unroll
  for (int ks = 0; ks < 2; ++ks)
#pragma unroll
    for (int qf = 0; qf < 2; ++qf) {
      int ra = __builtin_amdgcn_ds_bpermute(idx0, (int)pk[qf][2 * ks][0]);
      int rb = __builtin_amdgcn_ds_bpermute(idx0, (int)pk[qf][2 * ks + 1][0]);
      int rc = __builtin_amdgcn_ds_bpermute(idx0, (int)pk[qf][2 * ks][1]);
      int rd = __builtin_amdgcn_ds_bpermute(idx0, (int)pk[qf][2 * ks + 1][1]);
      int re = __builtin_amdgcn_ds_bpermute(idx1, (int)pk[qf][2 * ks][0]);
      int rf = __builtin_amdgcn_ds_bpermute(idx1, (int)pk[qf][2 * ks + 1][0]);
      int rg = __builtin_amdgcn_ds_bpermute(idx1, (int)pk[qf][2 * ks][1]);
      int rh = __builtin_amdgcn_ds_bpermute(idx1, (int)pk[qf][2 * ks + 1][1]);
      union { unsigned int u[4]; short8 v; } pw;
      pw.u[0] = hi ? (unsigned)rb : (unsigned)ra;
      pw.u[1] = hi ? (unsigned)rd : (unsigned)rc;
      pw.u[2] = hi ? (unsigned)rf : (unsigned)re;
      pw.u[3] = hi ? (unsigned)rh : (unsigned)rg;
      __builtin_amdgcn_s_setprio(1);
#pragma unroll
      for (int dc = 0; dc < 4; ++dc)
        oacc[qf][dc] = __builtin_amdgcn_mfma_f32_16x16x32_bf16(vfr[ks][dc], pw.v, oacc[qf][dc], 0, 0, 0);
      __builtin_amdgcn_s_setprio(0);
    }
}

// ---------------- MFMA flash attention (causal), 32-row paired strips -------------
// r8 structure (best known): LDS staging dbuf + both-sides swizzle + XCD-affine bh.
__global__ __launch_bounds__(256, 2) void attn_mfma(
    const unsigned short* __restrict__ Q,
    const unsigned short* __restrict__ K,
    const unsigned short* __restrict__ Vt,
    unsigned short* __restrict__ O) {
  __shared__ __align__(16) unsigned short ldsK[2][4096];  // 2 x 8KB (64x64 bf16, swizzled)
  __shared__ __align__(16) unsigned short ldsV[2][4096];
  const int tid = threadIdx.x;
  const int wave = tid >> 6, lane = tid & 63;
  const int g = lane >> 4, m = lane & 15;
  const int F = blockIdx.x;                  // 0..511
  const int q7 = F >> 3;
  const int bh = ((F & 7) << 3) | (q7 & 7);  // XCD-affine (r8: FETCH 131->25MB)
  const int bi = q7 >> 3;                    // 0..7 strip group
  const int b = bh >> 4, h = bh & 15;
  const int j = bi * 4 + wave;               // 0..31
  const int sA = j, sB = 63 - j;
  const int qA0 = sA * 32, qB0 = sB * 32;
  const int ntA = (sA >> 1) + 1, ntB = (sB >> 1) + 1;   // ntB > ntA
  const int ntBmax = ((63 - bi * 4) >> 1) + 1;          // block-uniform (wave 0's ntB)
  const size_t qkbase = ((size_t)b * Sv) * Dv + (size_t)h * 64;
  const size_t vtbase = (size_t)bh * 64 * Sv;
  const f32x4 zf = {0.f, 0.f, 0.f, 0.f};

  // per-lane swizzled staging source (slot s = chunk*64 + lane, chunk = i*4+wave)
  int srowS[2], scolS[2];
#pragma unroll
  for (int i = 0; i < 2; ++i) {
    int s = ((i * 4 + wave) << 6) + lane;
    int s2 = s ^ ((s >> 3) & 7);
    srowS[i] = s2 >> 3;
    scolS[i] = (s2 & 7) * 8;
  }

  short8 qA[2][2], qB[2][2];
#pragma unroll
  for (int qf = 0; qf < 2; ++qf)
#pragma unroll
    for (int ks = 0; ks < 2; ++ks) {
      qA[qf][ks] = *reinterpret_cast<const short8*>(
          Q + qkbase + (size_t)(qA0 + qf * 16 + m) * Dv + ks * 32 + g * 8);
      qB[qf][ks] = *reinterpret_cast<const short8*>(
          Q + qkbase + (size_t)(qB0 + qf * 16 + m) * Dv + ks * 32 + g * 8);
    }

  // LDS read offsets (shorts): frag (ks, row-block f) -> (f*16+m)*64 + (((ks*4+g)^(m&7))*8)
  int offL[2][4];
#pragma unroll
  for (int ks = 0; ks < 2; ++ks)
#pragma unroll
    for (int f = 0; f < 4; ++f)
      offL[ks][f] = (f * 16 + m) * 64 + ((((ks << 2) + g) ^ (m & 7)) * 8);

  f32x4 oA[2][4] = {}, oB[2][4] = {};
  float mA[2] = {-INFINITY, -INFINITY}, mB[2] = {-INFINITY, -INFINITY};
  float lA[2] = {0.f, 0.f}, lB[2] = {0.f, 0.f};

  const int idx0 = (((g & 1) << 5) + m) << 2;
  const int idx1 = idx0 + 64;
  const bool hi = (g >= 2);
  int qrelA = qA0 + m - 4 * g;
  int qrelB = qB0 + m - 4 * g;

  auto STAGE = [&](int c, int t) {
    const int kb = t << 6;
#pragma unroll
    for (int i = 0; i < 2; ++i) {
      gld_lds16(K + qkbase + (size_t)(kb + srowS[i]) * Dv + scolS[i],
                &ldsK[c][(i * 4 + wave) * 512]);
      gld_lds16(Vt + vtbase + (size_t)srowS[i] * Sv + kb + scolS[i],
                &ldsV[c][(i * 4 + wave) * 512]);
    }
  };

  STAGE(0, 0);
  __syncthreads();
  int cur = 0;

  for (int t = 0; t < ntBmax; ++t) {
    if (t + 1 < ntBmax) STAGE(cur ^ 1, t + 1);

    if (t < ntB) {
      const bool actA = (t < ntA);
      f32x4 sAacc[2][4], sBacc[2][4];
      short8 kfr[4];
#pragma unroll
      for (int kf = 0; kf < 4; ++kf)
        kfr[kf] = *reinterpret_cast<const short8*>(&ldsK[cur][offL[0][kf]]);
      __builtin_amdgcn_s_setprio(1);
#pragma unroll
      for (int qf = 0; qf < 2; ++qf)
#pragma unroll
        for (int kf = 0; kf < 4; ++kf)
          sBacc[qf][kf] = __builtin_amdgcn_mfma_f32_16x16x32_bf16(kfr[kf], qB[qf][0], zf, 0, 0, 0);
      if (actA)
#pragma unroll
        for (int qf = 0; qf < 2; ++qf)
#pragma unroll
          for (int kf = 0; kf < 4; ++kf)
            sAacc[qf][kf] = __builtin_amdgcn_mfma_f32_16x16x32_bf16(kfr[kf], qA[qf][0], zf, 0, 0, 0);
      __builtin_amdgcn_s_setprio(0);
#pragma unroll
      for (int kf = 0; kf < 4; ++kf)
        kfr[kf] = *reinterpret_cast<const short8*>(&ldsK[cur][offL[1][kf]]);
      __builtin_amdgcn_s_setprio(1);
#pragma unroll
      for (int qf = 0; qf < 2; ++qf)
#pragma unroll
        for (int kf = 0; kf < 4; ++kf)
          sBacc[qf][kf] = __builtin_amdgcn_mfma_f32_16x16x32_bf16(kfr[kf], qB[qf][1], sBacc[qf][kf], 0, 0, 0);
      if (actA)
#pragma unroll
        for (int qf = 0; qf < 2; ++qf)
#pragma unroll
          for (int kf = 0; kf < 4; ++kf)
            sAacc[qf][kf] = __builtin_amdgcn_mfma_f32_16x16x32_bf16(kfr[kf], qA[qf][1], sAacc[qf][kf], 0, 0, 0);
      __builtin_amdgcn_s_setprio(0);

      short8 vfr[2][4];
#pragma unroll
      for (int ks = 0; ks < 2; ++ks)
#pragma unroll
        for (int dc = 0; dc < 4; ++dc)
          vfr[ks][dc] = *reinterpret_cast<const short8*>(&ldsV[cur][offL[ks][dc]]);

      unsigned int pkB[2][4][2], pkA[2][4][2];
      softmax_strip(sBacc, t == ntB - 1, qrelB, mB, lB, oB, pkB);
      if (actA) softmax_strip(sAacc, t == ntA - 1, qrelA, mA, lA, oA, pkA);
      pv_strip(vfr, pkB, oB, idx0, idx1, hi);
      if (actA) pv_strip(vfr, pkA, oA, idx0, idx1, hi);

      qrelA -= 64; qrelB -= 64;
    }

    __syncthreads();   // drains this iteration's STAGE (vmcnt) + guards buffer reuse
    cur ^= 1;
  }

#pragma unroll
  for (int qf = 0; qf < 2; ++qf) {
    float rnA = 1.0f / lA[qf];
    float rnB = 1.0f / lB[qf];
    size_t rowA = (size_t)(qA0 + qf * 16 + m);
    size_t rowB = (size_t)(qB0 + qf * 16 + m);
#pragma unroll
    for (int dc = 0; dc < 4; ++dc) {
      ushort4 ov;
      ov.x = f2bf(oA[qf][dc][0] * rnA);
      ov.y = f2bf(oA[qf][dc][1] * rnA);
      ov.z = f2bf(oA[qf][dc][2] * rnA);
      ov.w = f2bf(oA[qf][dc][3] * rnA);
      *reinterpret_cast<ushort4*>(O + qkbase + rowA * Dv + dc * 16 + 4 * g) = ov;
      ov.x = f2bf(oB[qf][dc][0] * rnB);
      ov.y = f2bf(oB[qf][dc][1] * rnB);
      ov.z = f2bf(oB[qf][dc][2] * rnB);
      ov.w = f2bf(oB[qf][dc][3] * rnB);
      *reinterpret_cast<ushort4*>(O + qkbase + rowB * Dv + dc * 16 + 4 * g) = ov;
    }
  }
}

// ---------------- launcher ----------------
extern "C" void kernel_launch(void* const* d_in, const int* in_sizes, int n_in,
                              void* d_out, int out_size, void* d_ws, size_t ws_size,
                              hipStream_t stream) {
  const float* x   = (const float*)d_in[0];
  const int*   pos = (const int*)d_in[1];
  const float* wq  = (const float*)d_in[2];
  const float* wk  = (const float*)d_in[3];
  const float* wv  = (const float*)d_in[4];
  const float* wo  = (const float*)d_in[5];
  float* out = (float*)d_out;

  char* w = (char*)d_ws;
  unsigned short* xb    = (unsigned short*)(w);               // 16 MB: x bf16, later attn out
  unsigned short* wqkvb = (unsigned short*)(w + (16u << 20)); // 6 MB contiguous [3072][1024]
  unsigned short* wob   = (unsigned short*)(w + (22u << 20)); // 2 MB
  unsigned short* Qp    = (unsigned short*)(w + (24u << 20)); // 16 MB
  unsigned short* Kp    = (unsigned short*)(w + (40u << 20)); // 16 MB
  unsigned short* Vt    = (unsigned short*)(w + (56u << 20)); // 16 MB
  float*          tab   = (float*)(w + (72u << 20));          // 512 KB

  rope_table_k<<<(Sv * 32) / 256, 256, 0, stream>>>(pos, tab);
  cvt_f32_bf16<<<(Mv * Dv / 4) / 256, 256, 0, stream>>>(x, xb, Mv * Dv / 4);
  cvt3_f32_bf16<<<(3 * Dv * Dv / 4) / 256, 256, 0, stream>>>(wq, wk, wv, wqkvb);
  cvt_f32_bf16<<<(Dv * Dv / 4) / 256, 256, 0, stream>>>(wo, wob, Dv * Dv / 4);

  // fused QKV projection + RoPE + V-transpose
  gemm_qkv<<<dim3(3 * Dv / 128, Mv / 128), 256, 0, stream>>>(xb, wqkvb, Qp, Kp, Vt, tab);

  // attn out -> xb (x bf16 dead after gemm_qkv)
  attn_mfma<<<512, 256, 0, stream>>>(Qp, Kp, Vt, xb);

  gemm_bt_128<float><<<dim3(Dv / 128, Mv / 128), 256, 0, stream>>>(xb, wob, out, Mv, Dv, Dv);
}

// Round 11
// 215.890 us; speedup vs baseline: 1.1392x; 1.0558x over previous
//
#include <hip/hip_runtime.h>
#include <cstdint>
#include <cstddef>

#define Bv 4
#define Sv 2048
#define Hv 16
#define Dv 1024
#define Mv (Bv*Sv)   // 8192

typedef __attribute__((ext_vector_type(8))) short short8;
typedef __attribute__((ext_vector_type(8))) unsigned short ushort8v;
typedef __attribute__((ext_vector_type(4))) float f32x4;

__device__ inline float bf2f(unsigned short u) {
  union { unsigned int i; float f; } x; x.i = ((unsigned int)u) << 16; return x.f;
}
__device__ inline unsigned short f2bf(float f) {
  union { float f; unsigned int i; } x; x.f = f;
  unsigned int r = x.i + 0x7FFFu + ((x.i >> 16) & 1u);
  return (unsigned short)(r >> 16);
}

typedef __attribute__((address_space(1))) const unsigned short gu16;
typedef __attribute__((address_space(3))) unsigned short lu16;
__device__ inline void gld_lds16(const unsigned short* g, unsigned short* l) {
  __builtin_amdgcn_global_load_lds((gu16*)g, (lu16*)l, 16, 0, 0);
}

// ---------------- fused prelude: x/wqkv/wo cvt + RoPE table in ONE launch ----------------
__global__ __launch_bounds__(256) void prep_all(
    const float* __restrict__ x, const float* __restrict__ wq,
    const float* __restrict__ wk, const float* __restrict__ wv,
    const float* __restrict__ wo, const int* __restrict__ pos,
    unsigned short* __restrict__ xb, unsigned short* __restrict__ wqkvb,
    unsigned short* __restrict__ wob, float* __restrict__ tab) {
  const int bb = blockIdx.x, tid = threadIdx.x;
  if (bb < 8192) {                      // x: 2,097,152 float4
    int i = bb * 256 + tid;
    float4 v = reinterpret_cast<const float4*>(x)[i];
    ushort4 o;
    o.x = f2bf(v.x); o.y = f2bf(v.y); o.z = f2bf(v.z); o.w = f2bf(v.w);
    reinterpret_cast<ushort4*>(xb)[i] = o;
  } else if (bb < 11264) {              // wq|wk|wv -> contiguous [3072][1024]
    int i = (bb - 8192) * 256 + tid;
    int w = i >> 18, off = i & 262143;
    const float* src = (w == 0) ? wq : (w == 1) ? wk : wv;
    float4 v = reinterpret_cast<const float4*>(src)[off];
    ushort4 o;
    o.x = f2bf(v.x); o.y = f2bf(v.y); o.z = f2bf(v.z); o.w = f2bf(v.w);
    reinterpret_cast<ushort4*>(wqkvb)[i] = o;
  } else if (bb < 12288) {              // wo
    int i = (bb - 11264) * 256 + tid;
    float4 v = reinterpret_cast<const float4*>(wo)[i];
    ushort4 o;
    o.x = f2bf(v.x); o.y = f2bf(v.y); o.z = f2bf(v.z); o.w = f2bf(v.w);
    reinterpret_cast<ushort4*>(wob)[i] = o;
  } else {                              // RoPE cos/sin table: tab[s][0:32]=cos, [32:64]=sin
    int idx = (bb - 12288) * 256 + tid;  // Sv*32
    int s = idx >> 5, i = idx & 31;
    float p = (float)pos[s];
    float a = p * __builtin_exp2f(-0.41524101186092027f * (float)i);
    tab[(s << 6) + i]      = __builtin_cosf(a);
    tab[(s << 6) + 32 + i] = __builtin_sinf(a);
  }
}

// bijective XCD-chunk swizzle (T1, m204): valid when nwg % 8 == 0
__device__ __forceinline__ void xcd_swizzle(int& bm, int& bn) {
  const int nx = gridDim.x;
  const int nwg = nx * gridDim.y;
  int flat = blockIdx.y * nx + blockIdx.x;
  if ((nwg & 7) == 0) {
    int q = nwg >> 3;
    flat = (flat & 7) * q + (flat >> 3);
  }
  bm = (flat / nx) * 128;
  bn = (flat % nx) * 128;
}

// ---------------- bf16 GEMM core (m97): C = A[M,K] * B[N,K]^T ------------
__device__ inline void storeC(float* p, float v) { *p = v; }
__device__ inline void storeC(unsigned short* p, float v) { *p = f2bf(v); }

template <typename CT>
__global__ __launch_bounds__(256) void gemm_bt_128(
    const unsigned short* __restrict__ A,
    const unsigned short* __restrict__ B,
    CT* __restrict__ C,
    int M, int N, int K) {
  __shared__ unsigned short As[128 * 32];
  __shared__ unsigned short Bs[128 * 32];
  const int tid = threadIdx.x;
  const int wave = tid >> 6, lane = tid & 63;
  int bm, bn;
  xcd_swizzle(bm, bn);
  const int wr = (wave >> 1) * 64, wc = (wave & 1) * 64;

  f32x4 acc[4][4] = {};

  const int c0 = wave * 2, c1 = c0 + 1;
  const int sr0 = c0 * 16 + (lane >> 2);
  const int sr1 = c1 * 16 + (lane >> 2);
  const int scol = (lane & 3) * 8;

  const unsigned short* gA0 = A + (size_t)(bm + sr0) * K + scol;
  const unsigned short* gA1 = A + (size_t)(bm + sr1) * K + scol;
  const unsigned short* gB0 = B + (size_t)(bn + sr0) * K + scol;
  const unsigned short* gB1 = B + (size_t)(bn + sr1) * K + scol;
  unsigned short* lA0 = &As[c0 * 512];
  unsigned short* lA1 = &As[c1 * 512];
  unsigned short* lB0 = &Bs[c0 * 512];
  unsigned short* lB1 = &Bs[c1 * 512];

  const int fr = lane & 15;
  const int fk = (lane >> 4) * 8;

  for (int k0 = 0; k0 < K; k0 += 32) {
    gld_lds16(gA0 + k0, lA0);
    gld_lds16(gA1 + k0, lA1);
    gld_lds16(gB0 + k0, lB0);
    gld_lds16(gB1 + k0, lB1);
    __syncthreads();
    short8 af[4], bfr[4];
#pragma unroll
    for (int m = 0; m < 4; m++)
      af[m] = *reinterpret_cast<const short8*>(&As[(wr + m * 16 + fr) * 32 + fk]);
#pragma unroll
    for (int n = 0; n < 4; n++)
      bfr[n] = *reinterpret_cast<const short8*>(&Bs[(wc + n * 16 + fr) * 32 + fk]);
#pragma unroll
    for (int m = 0; m < 4; m++)
#pragma unroll
      for (int n = 0; n < 4; n++)
        acc[m][n] = __builtin_amdgcn_mfma_f32_16x16x32_bf16(af[m], bfr[n], acc[m][n], 0, 0, 0);
    __syncthreads();
  }

  const int er = (lane >> 4) * 4, ec = lane & 15;
#pragma unroll
  for (int m = 0; m < 4; m++)
#pragma unroll
    for (int n = 0; n < 4; n++)
#pragma unroll
      for (int r = 0; r < 4; r++) {
        int row = bm + wr + m * 16 + er + r;
        int col = bn + wc + n * 16 + ec;
        storeC(&C[(size_t)row * N + col], acc[m][n][r]);
      }
}

// ---------------- fused QKV GEMM: N=3072, epilogue does RoPE (Q,K) / transpose (V) -------
__global__ __launch_bounds__(256) void gemm_qkv(
    const unsigned short* __restrict__ A,
    const unsigned short* __restrict__ B,
    unsigned short* __restrict__ Qp,
    unsigned short* __restrict__ Kp,
    unsigned short* __restrict__ Vt,
    const float* __restrict__ tab) {
  const int K = Dv;
  __shared__ unsigned short As[128 * 32];
  __shared__ unsigned short Bs[128 * 32];
  const int tid = threadIdx.x;
  const int wave = tid >> 6, lane = tid & 63;
  int bm, bn;
  xcd_swizzle(bm, bn);
  const int wr = (wave >> 1) * 64, wc = (wave & 1) * 64;

  f32x4 acc[4][4] = {};

  const int c0 = wave * 2, c1 = c0 + 1;
  const int sr0 = c0 * 16 + (lane >> 2);
  const int sr1 = c1 * 16 + (lane >> 2);
  const int scol = (lane & 3) * 8;

  const unsigned short* gA0 = A + (size_t)(bm + sr0) * K + scol;
  const unsigned short* gA1 = A + (size_t)(bm + sr1) * K + scol;
  const unsigned short* gB0 = B + (size_t)(bn + sr0) * K + scol;
  const unsigned short* gB1 = B + (size_t)(bn + sr1) * K + scol;
  unsigned short* lA0 = &As[c0 * 512];
  unsigned short* lA1 = &As[c1 * 512];
  unsigned short* lB0 = &Bs[c0 * 512];
  unsigned short* lB1 = &Bs[c1 * 512];

  const int fr = lane & 15;
  const int fk = (lane >> 4) * 8;

  for (int k0 = 0; k0 < K; k0 += 32) {
    gld_lds16(gA0 + k0, lA0);
    gld_lds16(gA1 + k0, lA1);
    gld_lds16(gB0 + k0, lB0);
    gld_lds16(gB1 + k0, lB1);
    __syncthreads();
    short8 af[4], bfr[4];
#pragma unroll
    for (int m = 0; m < 4; m++)
      af[m] = *reinterpret_cast<const short8*>(&As[(wr + m * 16 + fr) * 32 + fk]);
#pragma unroll
    for (int n = 0; n < 4; n++)
      bfr[n] = *reinterpret_cast<const short8*>(&Bs[(wc + n * 16 + fr) * 32 + fk]);
#pragma unroll
    for (int m = 0; m < 4; m++)
#pragma unroll
      for (int n = 0; n < 4; n++)
        acc[m][n] = __builtin_amdgcn_mfma_f32_16x16x32_bf16(af[m], bfr[n], acc[m][n], 0, 0, 0);
    __syncthreads();
  }

  const int er = (lane >> 4) * 4, ec = lane & 15;
  const int region = bn >> 10;  // block-uniform: 0=Q, 1=K, 2=V
  if (region < 2) {
    unsigned short* T = (region == 0) ? Qp : Kp;
#pragma unroll
    for (int m = 0; m < 4; m++)
#pragma unroll
      for (int n = 0; n < 4; n++) {
        const int col = bn + wc + n * 16 + ec;
        const int ccol = col & (Dv - 1);
        const int ii = (ccol & 63) >> 1;
        const bool odd = col & 1;
#pragma unroll
        for (int r = 0; r < 4; r++) {
          int row = bm + wr + m * 16 + er + r;
          int s = row & (Sv - 1);
          float v = acc[m][n][r];
          float pv = __shfl_xor(v, 1);  // paired feature lives in lane^1 (ec^1)
          float cc = tab[(s << 6) + ii];
          float sn = tab[(s << 6) + 32 + ii];
          float o = odd ? __builtin_fmaf(pv, sn, v * cc)
                        : __builtin_fmaf(v, cc, -(pv * sn));
          T[(size_t)row * Dv + ccol] = f2bf(o);
        }
      }
  } else {
#pragma unroll
    for (int m = 0; m < 4; m++)
#pragma unroll
      for (int n = 0; n < 4; n++) {
        const int dfull = (bn - 2048) + wc + n * 16 + ec;  // h*64+d
        const int row0 = bm + wr + m * 16 + er;            // 4 consecutive rows (same b)
        const int bb = row0 >> 11, s = row0 & (Sv - 1);
        const size_t vtrow = ((size_t)bb * 16 + (dfull >> 6)) * 64 + (dfull & 63);
        ushort4 ov;
        ov.x = f2bf(acc[m][n][0]);
        ov.y = f2bf(acc[m][n][1]);
        ov.z = f2bf(acc[m][n][2]);
        ov.w = f2bf(acc[m][n][3]);
        *reinterpret_cast<ushort4*>(Vt + vtrow * Sv + s) = ov;
      }
  }
}

// ---------------- MFMA flash attention helpers (32-row strips) ----------------
// S^T layout per strip: lane (g=lane>>4, m=lane&15) holds S^T[k=16*kf+4g+r][q=qf*16+m].
__device__ __forceinline__ void softmax_strip(
    f32x4 (&sacc)[2][4], const bool lastt, const int qrel0,
    float (&mrun2)[2], float (&lrun)[2], f32x4 (&oacc)[2][4],
    unsigned int (&pk)[2][4][2]) {
  const float c1 = 0.18033688011112042f;  // log2(e)/8  (scale = 1/sqrt(64))
#pragma unroll
  for (int qf = 0; qf < 2; ++qf) {
    const int qrel = qrel0 + qf * 16;
    float pv[4][4];
    float mx = -INFINITY;
#pragma unroll
    for (int kf = 0; kf < 4; ++kf)
#pragma unroll
      for (int r = 0; r < 4; ++r) {
        float s = sacc[qf][kf][r];
        if (lastt) s = (kf * 16 + r > qrel) ? -INFINITY : s;
        pv[kf][r] = s;
        mx = fmaxf(mx, s);
      }
    mx = fmaxf(mx, __shfl_xor(mx, 16));
    mx = fmaxf(mx, __shfl_xor(mx, 32));
    float pm = mx * c1;
    if (__any(pm > mrun2[qf] + 8.0f)) {  // defer-max (T13)
      float m2 = fmaxf(mrun2[qf], pm);
      float sfq = __builtin_exp2f(mrun2[qf] - m2);
      lrun[qf] *= sfq;
#pragma unroll
      for (int dc = 0; dc < 4; ++dc)
#pragma unroll
        for (int r = 0; r < 4; ++r) oacc[qf][dc][r] *= sfq;
      mrun2[qf] = m2;
    }
    const float nm = -mrun2[qf];
    float ps = 0.f;
#pragma unroll
    for (int kf = 0; kf < 4; ++kf)
#pragma unroll
      for (int r = 0; r < 4; ++r) {
        float p = __builtin_exp2f(__builtin_fmaf(pv[kf][r], c1, nm));
        ps += p;
        pv[kf][r] = p;
      }
    ps += __shfl_xor(ps, 16);
    ps += __shfl_xor(ps, 32);
    lrun[qf] += ps;
#pragma unroll
    for (int kf = 0; kf < 4; ++kf)
#pragma unroll
      for (int hh = 0; hh < 2; ++hh) {
        unsigned int rr;
        asm("v_cvt_pk_bf16_f32 %0, %1, %2"
            : "=v"(rr) : "v"(pv[kf][2 * hh]), "v"(pv[kf][2 * hh + 1]));
        pk[qf][kf][hh] = rr;
      }
  }
}

// P^T B-frags via ds_bpermute: word t of target (g',m) = pk[2ks+(g'>>1)][t&1]
// from source lane 16*(2(g'&1)+(t>>1)) + m.
__device__ __forceinline__ void pv_strip(
    const short8 (&vfr)[2][4], const unsigned int (&pk)[2][4][2],
    f32x4 (&oacc)[2][4], const int idx0, const int idx1, const bool hi) {
#pragma unroll
  for (int ks = 0; ks < 2; ++ks)
#pragma unroll
    for (int qf = 0; qf < 2; ++qf) {
      int ra = __builtin_amdgcn_ds_bpermute(idx0, (int)pk[qf][2 * ks][0]);
      int rb = __builtin_amdgcn_ds_bpermute(idx0, (int)pk[qf][2 * ks + 1][0]);
      int rc = __builtin_amdgcn_ds_bpermute(idx0, (int)pk[qf][2 * ks][1]);
      int rd = __builtin_amdgcn_ds_bpermute(idx0, (int)pk[qf][2 * ks + 1][1]);
      int re = __builtin_amdgcn_ds_bpermute(idx1, (int)pk[qf][2 * ks][0]);
      int rf = __builtin_amdgcn_ds_bpermute(idx1, (int)pk[qf][2 * ks + 1][0]);
      int rg = __builtin_amdgcn_ds_bpermute(idx1, (int)pk[qf][2 * ks][1]);
      int rh = __builtin_amdgcn_ds_bpermute(idx1, (int)pk[qf][2 * ks + 1][1]);
      union { unsigned int u[4]; short8 v; } pw;
      pw.u[0] = hi ? (unsigned)rb : (unsigned)ra;
      pw.u[1] = hi ? (unsigned)rd : (unsigned)rc;
      pw.u[2] = hi ? (unsigned)rf : (unsigned)re;
      pw.u[3] = hi ? (unsigned)rh : (unsigned)rg;
      __builtin_amdgcn_s_setprio(1);
#pragma unroll
      for (int dc = 0; dc < 4; ++dc)
        oacc[qf][dc] = __builtin_amdgcn_mfma_f32_16x16x32_bf16(vfr[ks][dc], pw.v, oacc[qf][dc], 0, 0, 0);
      __builtin_amdgcn_s_setprio(0);
    }
}

// ---------------- MFMA flash attention (causal), 32-row paired strips -------------
// r8 structure + T4 counted-vmcnt pipeline: TRIPLE-buffered K/V staging, ONE raw
// s_barrier per tile, vmcnt(4) (= STAGE(t+1)'s 4 loads stay in flight across the
// barrier — never drain to 0 mid-loop). WAR-safe: buffer b is overwritten (STAGE
// t+2, issued after barrier t) one full barrier after its last read (compute t-1).
// RAW-safe: each wave's vmcnt(4) before barrier t confirms its own STAGE(t) done.
__global__ __launch_bounds__(256, 2) void attn_mfma(
    const unsigned short* __restrict__ Q,
    const unsigned short* __restrict__ K,
    const unsigned short* __restrict__ Vt,
    unsigned short* __restrict__ O) {
  __shared__ __align__(16) unsigned short ldsK[3][4096];  // 3 x 8KB (64x64 bf16, swizzled)
  __shared__ __align__(16) unsigned short ldsV[3][4096];
  const int tid = threadIdx.x;
  const int wave = tid >> 6, lane = tid & 63;
  const int g = lane >> 4, m = lane & 15;
  const int F = blockIdx.x;                  // 0..511
  const int q7 = F >> 3;
  const int bh = ((F & 7) << 3) | (q7 & 7);  // XCD-affine (r8: FETCH 131->25MB)
  const int bi = q7 >> 3;                    // 0..7 strip group
  const int b = bh >> 4, h = bh & 15;
  const int j = bi * 4 + wave;               // 0..31
  const int sA = j, sB = 63 - j;
  const int qA0 = sA * 32, qB0 = sB * 32;
  const int ntA = (sA >> 1) + 1, ntB = (sB >> 1) + 1;   // ntB > ntA
  const int ntBmax = ((63 - bi * 4) >> 1) + 1;          // block-uniform (wave 0's ntB), >= 18
  const size_t qkbase = ((size_t)b * Sv) * Dv + (size_t)h * 64;
  const size_t vtbase = (size_t)bh * 64 * Sv;
  const f32x4 zf = {0.f, 0.f, 0.f, 0.f};

  // per-lane swizzled staging source (slot s = chunk*64 + lane, chunk = i*4+wave)
  int srowS[2], scolS[2];
#pragma unroll
  for (int i = 0; i < 2; ++i) {
    int s = ((i * 4 + wave) << 6) + lane;
    int s2 = s ^ ((s >> 3) & 7);
    srowS[i] = s2 >> 3;
    scolS[i] = (s2 & 7) * 8;
  }

  short8 qA[2][2], qB[2][2];
#pragma unroll
  for (int qf = 0; qf < 2; ++qf)
#pragma unroll
    for (int ks = 0; ks < 2; ++ks) {
      qA[qf][ks] = *reinterpret_cast<const short8*>(
          Q + qkbase + (size_t)(qA0 + qf * 16 + m) * Dv + ks * 32 + g * 8);
      qB[qf][ks] = *reinterpret_cast<const short8*>(
          Q + qkbase + (size_t)(qB0 + qf * 16 + m) * Dv + ks * 32 + g * 8);
    }

  // LDS read offsets (shorts): frag (ks, row-block f) -> (f*16+m)*64 + (((ks*4+g)^(m&7))*8)
  int offL[2][4];
#pragma unroll
  for (int ks = 0; ks < 2; ++ks)
#pragma unroll
    for (int f = 0; f < 4; ++f)
      offL[ks][f] = (f * 16 + m) * 64 + ((((ks << 2) + g) ^ (m & 7)) * 8);

  f32x4 oA[2][4] = {}, oB[2][4] = {};
  float mA[2] = {-INFINITY, -INFINITY}, mB[2] = {-INFINITY, -INFINITY};
  float lA[2] = {0.f, 0.f}, lB[2] = {0.f, 0.f};

  const int idx0 = (((g & 1) << 5) + m) << 2;
  const int idx1 = idx0 + 64;
  const bool hi = (g >= 2);
  int qrelA = qA0 + m - 4 * g;
  int qrelB = qB0 + m - 4 * g;

  auto STAGE = [&](int c, int t) {
    const int kb = t << 6;
#pragma unroll
    for (int i = 0; i < 2; ++i) {
      gld_lds16(K + qkbase + (size_t)(kb + srowS[i]) * Dv + scolS[i],
                &ldsK[c][(i * 4 + wave) * 512]);
      gld_lds16(Vt + vtbase + (size_t)srowS[i] * Sv + kb + scolS[i],
                &ldsV[c][(i * 4 + wave) * 512]);
    }
  };

  STAGE(0, 0);          // 4 loads/thread
  STAGE(1, 1);          // ntBmax >= 18 always
  int cur = 0, bs = 2;  // compute buffer, stage buffer (= (t+2)%3)

  for (int t = 0; t < ntBmax; ++t) {
    // wait for STAGE(t) only: 4 newer loads (STAGE(t+1)) may stay in flight (T4)
    if (t + 1 < ntBmax) {
      asm volatile("s_waitcnt vmcnt(4)" ::: "memory");
    } else {
      asm volatile("s_waitcnt vmcnt(0)" ::: "memory");
    }
    __builtin_amdgcn_sched_barrier(0);
    __builtin_amdgcn_s_barrier();      // raw barrier: no vmcnt drain
    if (t + 2 < ntBmax) STAGE(bs, t + 2);

    if (t < ntB) {
      const bool actA = (t < ntA);
      f32x4 sAacc[2][4], sBacc[2][4];
      short8 kfr[4];
#pragma unroll
      for (int kf = 0; kf < 4; ++kf)
        kfr[kf] = *reinterpret_cast<const short8*>(&ldsK[cur][offL[0][kf]]);
      __builtin_amdgcn_s_setprio(1);
#pragma unroll
      for (int qf = 0; qf < 2; ++qf)
#pragma unroll
        for (int kf = 0; kf < 4; ++kf)
          sBacc[qf][kf] = __builtin_amdgcn_mfma_f32_16x16x32_bf16(kfr[kf], qB[qf][0], zf, 0, 0, 0);
      if (actA)
#pragma unroll
        for (int qf = 0; qf < 2; ++qf)
#pragma unroll
          for (int kf = 0; kf < 4; ++kf)
            sAacc[qf][kf] = __builtin_amdgcn_mfma_f32_16x16x32_bf16(kfr[kf], qA[qf][0], zf, 0, 0, 0);
      __builtin_amdgcn_s_setprio(0);
#pragma unroll
      for (int kf = 0; kf < 4; ++kf)
        kfr[kf] = *reinterpret_cast<const short8*>(&ldsK[cur][offL[1][kf]]);
      __builtin_amdgcn_s_setprio(1);
#pragma unroll
      for (int qf = 0; qf < 2; ++qf)
#pragma unroll
        for (int kf = 0; kf < 4; ++kf)
          sBacc[qf][kf] = __builtin_amdgcn_mfma_f32_16x16x32_bf16(kfr[kf], qB[qf][1], sBacc[qf][kf], 0, 0, 0);
      if (actA)
#pragma unroll
        for (int qf = 0; qf < 2; ++qf)
#pragma unroll
          for (int kf = 0; kf < 4; ++kf)
            sAacc[qf][kf] = __builtin_amdgcn_mfma_f32_16x16x32_bf16(kfr[kf], qA[qf][1], sAacc[qf][kf], 0, 0, 0);
      __builtin_amdgcn_s_setprio(0);

      short8 vfr[2][4];
#pragma unroll
      for (int ks = 0; ks < 2; ++ks)
#pragma unroll
        for (int dc = 0; dc < 4; ++dc)
          vfr[ks][dc] = *reinterpret_cast<const short8*>(&ldsV[cur][offL[ks][dc]]);

      unsigned int pkB[2][4][2], pkA[2][4][2];
      softmax_strip(sBacc, t == ntB - 1, qrelB, mB, lB, oB, pkB);
      if (actA) softmax_strip(sAacc, t == ntA - 1, qrelA, mA, lA, oA, pkA);
      pv_strip(vfr, pkB, oB, idx0, idx1, hi);
      if (actA) pv_strip(vfr, pkA, oA, idx0, idx1, hi);

      qrelA -= 64; qrelB -= 64;
    }

    cur = (cur == 2) ? 0 : cur + 1;
    bs = (bs == 2) ? 0 : bs + 1;
  }

#pragma unroll
  for (int qf = 0; qf < 2; ++qf) {
    float rnA = 1.0f / lA[qf];
    float rnB = 1.0f / lB[qf];
    size_t rowA = (size_t)(qA0 + qf * 16 + m);
    size_t rowB = (size_t)(qB0 + qf * 16 + m);
#pragma unroll
    for (int dc = 0; dc < 4; ++dc) {
      ushort4 ov;
      ov.x = f2bf(oA[qf][dc][0] * rnA);
      ov.y = f2bf(oA[qf][dc][1] * rnA);
      ov.z = f2bf(oA[qf][dc][2] * rnA);
      ov.w = f2bf(oA[qf][dc][3] * rnA);
      *reinterpret_cast<ushort4*>(O + qkbase + rowA * Dv + dc * 16 + 4 * g) = ov;
      ov.x = f2bf(oB[qf][dc][0] * rnB);
      ov.y = f2bf(oB[qf][dc][1] * rnB);
      ov.z = f2bf(oB[qf][dc][2] * rnB);
      ov.w = f2bf(oB[qf][dc][3] * rnB);
      *reinterpret_cast<ushort4*>(O + qkbase + rowB * Dv + dc * 16 + 4 * g) = ov;
    }
  }
}

// ---------------- launcher ----------------
extern "C" void kernel_launch(void* const* d_in, const int* in_sizes, int n_in,
                              void* d_out, int out_size, void* d_ws, size_t ws_size,
                              hipStream_t stream) {
  const float* x   = (const float*)d_in[0];
  const int*   pos = (const int*)d_in[1];
  const float* wq  = (const float*)d_in[2];
  const float* wk  = (const float*)d_in[3];
  const float* wv  = (const float*)d_in[4];
  const float* wo  = (const float*)d_in[5];
  float* out = (float*)d_out;

  char* w = (char*)d_ws;
  unsigned short* xb    = (unsigned short*)(w);               // 16 MB: x bf16, later attn out
  unsigned short* wqkvb = (unsigned short*)(w + (16u << 20)); // 6 MB contiguous [3072][1024]
  unsigned short* wob   = (unsigned short*)(w + (22u << 20)); // 2 MB
  unsigned short* Qp    = (unsigned short*)(w + (24u << 20)); // 16 MB
  unsigned short* Kp    = (unsigned short*)(w + (40u << 20)); // 16 MB
  unsigned short* Vt    = (unsigned short*)(w + (56u << 20)); // 16 MB
  float*          tab   = (float*)(w + (72u << 20));          // 512 KB

  // fused prelude: all cvts + RoPE table in one launch
  prep_all<<<12544, 256, 0, stream>>>(x, wq, wk, wv, wo, pos, xb, wqkvb, wob, tab);

  // fused QKV projection + RoPE + V-transpose
  gemm_qkv<<<dim3(3 * Dv / 128, Mv / 128), 256, 0, stream>>>(xb, wqkvb, Qp, Kp, Vt, tab);

  // attn out -> xb (x bf16 dead after gemm_qkv)
  attn_mfma<<<512, 256, 0, stream>>>(Qp, Kp, Vt, xb);

  gemm_bt_128<float><<<dim3(Dv / 128, Mv / 128), 256, 0, stream>>>(xb, wob, out, Mv, Dv, Dv);
}

// Round 12
// 201.682 us; speedup vs baseline: 1.2194x; 1.0704x over previous
//
#include <hip/hip_runtime.h>
#include <cstdint>
#include <cstddef>

#define Bv 4
#define Sv 2048
#define Hv 16
#define Dv 1024
#define Mv (Bv*Sv)   // 8192

typedef __attribute__((ext_vector_type(8))) short short8;
typedef __attribute__((ext_vector_type(8))) unsigned short ushort8v;
typedef __attribute__((ext_vector_type(4))) float f32x4;

__device__ inline float bf2f(unsigned short u) {
  union { unsigned int i; float f; } x; x.i = ((unsigned int)u) << 16; return x.f;
}
__device__ inline unsigned short f2bf(float f) {
  union { float f; unsigned int i; } x; x.f = f;
  unsigned int r = x.i + 0x7FFFu + ((x.i >> 16) & 1u);
  return (unsigned short)(r >> 16);
}

typedef __attribute__((address_space(1))) const unsigned short gu16;
typedef __attribute__((address_space(3))) unsigned short lu16;
__device__ inline void gld_lds16(const unsigned short* g, unsigned short* l) {
  __builtin_amdgcn_global_load_lds((gu16*)g, (lu16*)l, 16, 0, 0);
}

// ---------------- fused prelude: x/wqkv/wo cvt + RoPE table in ONE launch ----------------
__global__ __launch_bounds__(256) void prep_all(
    const float* __restrict__ x, const float* __restrict__ wq,
    const float* __restrict__ wk, const float* __restrict__ wv,
    const float* __restrict__ wo, const int* __restrict__ pos,
    unsigned short* __restrict__ xb, unsigned short* __restrict__ wqkvb,
    unsigned short* __restrict__ wob, float* __restrict__ tab) {
  const int bb = blockIdx.x, tid = threadIdx.x;
  if (bb < 8192) {                      // x: 2,097,152 float4
    int i = bb * 256 + tid;
    float4 v = reinterpret_cast<const float4*>(x)[i];
    ushort4 o;
    o.x = f2bf(v.x); o.y = f2bf(v.y); o.z = f2bf(v.z); o.w = f2bf(v.w);
    reinterpret_cast<ushort4*>(xb)[i] = o;
  } else if (bb < 11264) {              // wq|wk|wv -> contiguous [3072][1024]
    int i = (bb - 8192) * 256 + tid;
    int w = i >> 18, off = i & 262143;
    const float* src = (w == 0) ? wq : (w == 1) ? wk : wv;
    float4 v = reinterpret_cast<const float4*>(src)[off];
    ushort4 o;
    o.x = f2bf(v.x); o.y = f2bf(v.y); o.z = f2bf(v.z); o.w = f2bf(v.w);
    reinterpret_cast<ushort4*>(wqkvb)[i] = o;
  } else if (bb < 12288) {              // wo
    int i = (bb - 11264) * 256 + tid;
    float4 v = reinterpret_cast<const float4*>(wo)[i];
    ushort4 o;
    o.x = f2bf(v.x); o.y = f2bf(v.y); o.z = f2bf(v.z); o.w = f2bf(v.w);
    reinterpret_cast<ushort4*>(wob)[i] = o;
  } else {                              // RoPE cos/sin table
    int idx = (bb - 12288) * 256 + tid;  // Sv*32
    int s = idx >> 5, i = idx & 31;
    float p = (float)pos[s];
    float a = p * __builtin_exp2f(-0.41524101186092027f * (float)i);
    tab[(s << 6) + i]      = __builtin_cosf(a);
    tab[(s << 6) + 32 + i] = __builtin_sinf(a);
  }
}

// bijective XCD-chunk swizzle (T1, m204): valid when nwg % 8 == 0
__device__ __forceinline__ void xcd_swizzle(int& bm, int& bn) {
  const int nx = gridDim.x;
  const int nwg = nx * gridDim.y;
  int flat = blockIdx.y * nx + blockIdx.x;
  if ((nwg & 7) == 0) {
    int q = nwg >> 3;
    flat = (flat & 7) * q + (flat >> 3);
  }
  bm = (flat / nx) * 128;
  bn = (flat % nx) * 128;
}

// ---------------- bf16 GEMM (m97-derived, BK=64 + XOR-swizzled LDS) ------------
// C[M,N] = A[M,K] * B[N,K]^T. LDS tile 128x64 per matrix (16KB each).
// Both-sides involution (verified in attn r6): staging source granule
// cb ^ (row&7) written linearly; reads at granule (colblk ^ (fr&7)).
__device__ inline void storeC(float* p, float v) { *p = v; }
__device__ inline void storeC(unsigned short* p, float v) { *p = f2bf(v); }

template <typename CT>
__global__ __launch_bounds__(256) void gemm_bt_128(
    const unsigned short* __restrict__ A,
    const unsigned short* __restrict__ B,
    CT* __restrict__ C,
    int M, int N, int K) {
  __shared__ unsigned short As[128 * 64];
  __shared__ unsigned short Bs[128 * 64];
  const int tid = threadIdx.x;
  const int wave = tid >> 6, lane = tid & 63;
  int bm, bn;
  xcd_swizzle(bm, bn);
  const int wr = (wave >> 1) * 64, wc = (wave & 1) * 64;

  f32x4 acc[4][4] = {};

  // staging: chunk c = i*4+wave covers rows c*8..c*8+7 (8 rows x 64 cols = 512 shorts)
  int srow[4], scol[4];
#pragma unroll
  for (int i = 0; i < 4; ++i) {
    int c = i * 4 + wave;
    srow[i] = c * 8 + (lane >> 3);
    scol[i] = ((lane & 7) ^ ((lane >> 3) & 7)) * 8;
  }

  const int fr = lane & 15;
  const int g_ = lane >> 4;  // 0..3
  int offA[2][4], offB[2][4];
#pragma unroll
  for (int kh = 0; kh < 2; ++kh)
#pragma unroll
    for (int m = 0; m < 4; ++m) {
      offA[kh][m] = (wr + m * 16 + fr) * 64 + ((((kh << 2) + g_) ^ (fr & 7)) * 8);
      offB[kh][m] = (wc + m * 16 + fr) * 64 + ((((kh << 2) + g_) ^ (fr & 7)) * 8);
    }

  for (int k0 = 0; k0 < K; k0 += 64) {
#pragma unroll
    for (int i = 0; i < 4; ++i) {
      gld_lds16(A + (size_t)(bm + srow[i]) * K + k0 + scol[i], &As[(i * 4 + wave) * 512]);
      gld_lds16(B + (size_t)(bn + srow[i]) * K + k0 + scol[i], &Bs[(i * 4 + wave) * 512]);
    }
    __syncthreads();   // drains vmcnt before s_barrier
#pragma unroll
    for (int kh = 0; kh < 2; ++kh) {
      short8 af[4], bfr[4];
#pragma unroll
      for (int m = 0; m < 4; m++)
        af[m] = *reinterpret_cast<const short8*>(&As[offA[kh][m]]);
#pragma unroll
      for (int n = 0; n < 4; n++)
        bfr[n] = *reinterpret_cast<const short8*>(&Bs[offB[kh][n]]);
#pragma unroll
      for (int m = 0; m < 4; m++)
#pragma unroll
        for (int n = 0; n < 4; n++)
          acc[m][n] = __builtin_amdgcn_mfma_f32_16x16x32_bf16(af[m], bfr[n], acc[m][n], 0, 0, 0);
    }
    __syncthreads();
  }

  const int er = (lane >> 4) * 4, ec = lane & 15;
#pragma unroll
  for (int m = 0; m < 4; m++)
#pragma unroll
    for (int n = 0; n < 4; n++)
#pragma unroll
      for (int r = 0; r < 4; r++) {
        int row = bm + wr + m * 16 + er + r;
        int col = bn + wc + n * 16 + ec;
        storeC(&C[(size_t)row * N + col], acc[m][n][r]);
      }
}

// ---------------- fused QKV GEMM (BK=64): epilogue RoPE (Q,K) / transpose (V) -------
__global__ __launch_bounds__(256) void gemm_qkv(
    const unsigned short* __restrict__ A,
    const unsigned short* __restrict__ B,
    unsigned short* __restrict__ Qp,
    unsigned short* __restrict__ Kp,
    unsigned short* __restrict__ Vt,
    const float* __restrict__ tab) {
  const int K = Dv;
  __shared__ unsigned short As[128 * 64];
  __shared__ unsigned short Bs[128 * 64];
  const int tid = threadIdx.x;
  const int wave = tid >> 6, lane = tid & 63;
  int bm, bn;
  xcd_swizzle(bm, bn);
  const int wr = (wave >> 1) * 64, wc = (wave & 1) * 64;

  f32x4 acc[4][4] = {};

  int srow[4], scol[4];
#pragma unroll
  for (int i = 0; i < 4; ++i) {
    int c = i * 4 + wave;
    srow[i] = c * 8 + (lane >> 3);
    scol[i] = ((lane & 7) ^ ((lane >> 3) & 7)) * 8;
  }

  const int fr = lane & 15;
  const int g_ = lane >> 4;
  int offA[2][4], offB[2][4];
#pragma unroll
  for (int kh = 0; kh < 2; ++kh)
#pragma unroll
    for (int m = 0; m < 4; ++m) {
      offA[kh][m] = (wr + m * 16 + fr) * 64 + ((((kh << 2) + g_) ^ (fr & 7)) * 8);
      offB[kh][m] = (wc + m * 16 + fr) * 64 + ((((kh << 2) + g_) ^ (fr & 7)) * 8);
    }

  for (int k0 = 0; k0 < K; k0 += 64) {
#pragma unroll
    for (int i = 0; i < 4; ++i) {
      gld_lds16(A + (size_t)(bm + srow[i]) * K + k0 + scol[i], &As[(i * 4 + wave) * 512]);
      gld_lds16(B + (size_t)(bn + srow[i]) * K + k0 + scol[i], &Bs[(i * 4 + wave) * 512]);
    }
    __syncthreads();
#pragma unroll
    for (int kh = 0; kh < 2; ++kh) {
      short8 af[4], bfr[4];
#pragma unroll
      for (int m = 0; m < 4; m++)
        af[m] = *reinterpret_cast<const short8*>(&As[offA[kh][m]]);
#pragma unroll
      for (int n = 0; n < 4; n++)
        bfr[n] = *reinterpret_cast<const short8*>(&Bs[offB[kh][n]]);
#pragma unroll
      for (int m = 0; m < 4; m++)
#pragma unroll
        for (int n = 0; n < 4; n++)
          acc[m][n] = __builtin_amdgcn_mfma_f32_16x16x32_bf16(af[m], bfr[n], acc[m][n], 0, 0, 0);
    }
    __syncthreads();
  }

  const int er = (lane >> 4) * 4, ec = lane & 15;
  const int region = bn >> 10;  // block-uniform: 0=Q, 1=K, 2=V
  if (region < 2) {
    unsigned short* T = (region == 0) ? Qp : Kp;
#pragma unroll
    for (int m = 0; m < 4; m++)
#pragma unroll
      for (int n = 0; n < 4; n++) {
        const int col = bn + wc + n * 16 + ec;
        const int ccol = col & (Dv - 1);
        const int ii = (ccol & 63) >> 1;
        const bool odd = col & 1;
#pragma unroll
        for (int r = 0; r < 4; r++) {
          int row = bm + wr + m * 16 + er + r;
          int s = row & (Sv - 1);
          float v = acc[m][n][r];
          float pv = __shfl_xor(v, 1);  // paired feature lives in lane^1 (ec^1)
          float cc = tab[(s << 6) + ii];
          float sn = tab[(s << 6) + 32 + ii];
          float o = odd ? __builtin_fmaf(pv, sn, v * cc)
                        : __builtin_fmaf(v, cc, -(pv * sn));
          T[(size_t)row * Dv + ccol] = f2bf(o);
        }
      }
  } else {
#pragma unroll
    for (int m = 0; m < 4; m++)
#pragma unroll
      for (int n = 0; n < 4; n++) {
        const int dfull = (bn - 2048) + wc + n * 16 + ec;  // h*64+d
        const int row0 = bm + wr + m * 16 + er;            // 4 consecutive rows (same b)
        const int bb = row0 >> 11, s = row0 & (Sv - 1);
        const size_t vtrow = ((size_t)bb * 16 + (dfull >> 6)) * 64 + (dfull & 63);
        ushort4 ov;
        ov.x = f2bf(acc[m][n][0]);
        ov.y = f2bf(acc[m][n][1]);
        ov.z = f2bf(acc[m][n][2]);
        ov.w = f2bf(acc[m][n][3]);
        *reinterpret_cast<ushort4*>(Vt + vtrow * Sv + s) = ov;
      }
  }
}

// ---------------- MFMA flash attention helpers (32-row strips) ----------------
// S^T layout per strip: lane (g=lane>>4, m=lane&15) holds S^T[k=16*kf+4g+r][q=qf*16+m].
// MASKED template: causal mask VALU emitted ONLY in the peeled last-tile call.
template <bool MASKED>
__device__ __forceinline__ void softmax_strip(
    f32x4 (&sacc)[2][4], const int qrel0,
    float (&mrun2)[2], float (&lrun)[2], f32x4 (&oacc)[2][4],
    unsigned int (&pk)[2][4][2]) {
  const float c1 = 0.18033688011112042f;  // log2(e)/8  (scale = 1/sqrt(64))
#pragma unroll
  for (int qf = 0; qf < 2; ++qf) {
    const int qrel = qrel0 + qf * 16;
    float pv[4][4];
    float mx = -INFINITY;
#pragma unroll
    for (int kf = 0; kf < 4; ++kf)
#pragma unroll
      for (int r = 0; r < 4; ++r) {
        float s = sacc[qf][kf][r];
        if (MASKED) s = (kf * 16 + r > qrel) ? -INFINITY : s;
        pv[kf][r] = s;
        mx = fmaxf(mx, s);
      }
    mx = fmaxf(mx, __shfl_xor(mx, 16));
    mx = fmaxf(mx, __shfl_xor(mx, 32));
    float pm = mx * c1;
    if (__any(pm > mrun2[qf] + 8.0f)) {  // defer-max (T13)
      float m2 = fmaxf(mrun2[qf], pm);
      float sfq = __builtin_exp2f(mrun2[qf] - m2);
      lrun[qf] *= sfq;
#pragma unroll
      for (int dc = 0; dc < 4; ++dc)
#pragma unroll
        for (int r = 0; r < 4; ++r) oacc[qf][dc][r] *= sfq;
      mrun2[qf] = m2;
    }
    const float nm = -mrun2[qf];
    float ps = 0.f;
#pragma unroll
    for (int kf = 0; kf < 4; ++kf)
#pragma unroll
      for (int r = 0; r < 4; ++r) {
        float p = __builtin_exp2f(__builtin_fmaf(pv[kf][r], c1, nm));
        ps += p;
        pv[kf][r] = p;
      }
    ps += __shfl_xor(ps, 16);
    ps += __shfl_xor(ps, 32);
    lrun[qf] += ps;
#pragma unroll
    for (int kf = 0; kf < 4; ++kf)
#pragma unroll
      for (int hh = 0; hh < 2; ++hh) {
        unsigned int rr;
        asm("v_cvt_pk_bf16_f32 %0, %1, %2"
            : "=v"(rr) : "v"(pv[kf][2 * hh]), "v"(pv[kf][2 * hh + 1]));
        pk[qf][kf][hh] = rr;
      }
  }
}

// P^T B-frags via ds_bpermute: word t of target (g',m) = pk[2ks+(g'>>1)][t&1]
// from source lane 16*(2(g'&1)+(t>>1)) + m.
__device__ __forceinline__ void pv_strip(
    const short8 (&vfr)[2][4], const unsigned int (&pk)[2][4][2],
    f32x4 (&oacc)[2][4], const int idx0, const int idx1, const bool hi) {
#pragma unroll
  for (int ks = 0; ks < 2; ++ks)
#pragma unroll
    for (int qf = 0; qf < 2; ++qf) {
      int ra = __builtin_amdgcn_ds_bpermute(idx0, (int)pk[qf][2 * ks][0]);
      int rb = __builtin_amdgcn_ds_bpermute(idx0, (int)pk[qf][2 * ks + 1][0]);
      int rc = __builtin_amdgcn_ds_bpermute(idx0, (int)pk[qf][2 * ks][1]);
      int rd = __builtin_amdgcn_ds_bpermute(idx0, (int)pk[qf][2 * ks + 1][1]);
      int re = __builtin_amdgcn_ds_bpermute(idx1, (int)pk[qf][2 * ks][0]);
      int rf = __builtin_amdgcn_ds_bpermute(idx1, (int)pk[qf][2 * ks + 1][0]);
      int rg = __builtin_amdgcn_ds_bpermute(idx1, (int)pk[qf][2 * ks][1]);
      int rh = __builtin_amdgcn_ds_bpermute(idx1, (int)pk[qf][2 * ks + 1][1]);
      union { unsigned int u[4]; short8 v; } pw;
      pw.u[0] = hi ? (unsigned)rb : (unsigned)ra;
      pw.u[1] = hi ? (unsigned)rd : (unsigned)rc;
      pw.u[2] = hi ? (unsigned)rf : (unsigned)re;
      pw.u[3] = hi ? (unsigned)rh : (unsigned)rg;
      __builtin_amdgcn_s_setprio(1);
#pragma unroll
      for (int dc = 0; dc < 4; ++dc)
        oacc[qf][dc] = __builtin_amdgcn_mfma_f32_16x16x32_bf16(vfr[ks][dc], pw.v, oacc[qf][dc], 0, 0, 0);
      __builtin_amdgcn_s_setprio(0);
    }
}

// ---------------- MFMA flash attention (causal), 32-row paired strips -------------
// r11 structure: triple-buffered staging, counted vmcnt(4), raw barrier, XCD-affine bh.
// + masked-last-tile peel (steady-state iterations carry no mask VALU).
__global__ __launch_bounds__(256, 2) void attn_mfma(
    const unsigned short* __restrict__ Q,
    const unsigned short* __restrict__ K,
    const unsigned short* __restrict__ Vt,
    unsigned short* __restrict__ O) {
  __shared__ __align__(16) unsigned short ldsK[3][4096];  // 3 x 8KB (64x64 bf16, swizzled)
  __shared__ __align__(16) unsigned short ldsV[3][4096];
  const int tid = threadIdx.x;
  const int wave = tid >> 6, lane = tid & 63;
  const int g = lane >> 4, m = lane & 15;
  const int F = blockIdx.x;                  // 0..511
  const int q7 = F >> 3;
  const int bh = ((F & 7) << 3) | (q7 & 7);  // XCD-affine (r8: FETCH 131->25MB)
  const int bi = q7 >> 3;                    // 0..7 strip group
  const int b = bh >> 4, h = bh & 15;
  const int j = bi * 4 + wave;               // 0..31
  const int sA = j, sB = 63 - j;
  const int qA0 = sA * 32, qB0 = sB * 32;
  const int ntA = (sA >> 1) + 1, ntB = (sB >> 1) + 1;   // ntB > ntA
  const int ntBmax = ((63 - bi * 4) >> 1) + 1;          // block-uniform, >= 18
  const size_t qkbase = ((size_t)b * Sv) * Dv + (size_t)h * 64;
  const size_t vtbase = (size_t)bh * 64 * Sv;
  const f32x4 zf = {0.f, 0.f, 0.f, 0.f};

  int srowS[2], scolS[2];
#pragma unroll
  for (int i = 0; i < 2; ++i) {
    int s = ((i * 4 + wave) << 6) + lane;
    int s2 = s ^ ((s >> 3) & 7);
    srowS[i] = s2 >> 3;
    scolS[i] = (s2 & 7) * 8;
  }

  short8 qA[2][2], qB[2][2];
#pragma unroll
  for (int qf = 0; qf < 2; ++qf)
#pragma unroll
    for (int ks = 0; ks < 2; ++ks) {
      qA[qf][ks] = *reinterpret_cast<const short8*>(
          Q + qkbase + (size_t)(qA0 + qf * 16 + m) * Dv + ks * 32 + g * 8);
      qB[qf][ks] = *reinterpret_cast<const short8*>(
          Q + qkbase + (size_t)(qB0 + qf * 16 + m) * Dv + ks * 32 + g * 8);
    }

  int offL[2][4];
#pragma unroll
  for (int ks = 0; ks < 2; ++ks)
#pragma unroll
    for (int f = 0; f < 4; ++f)
      offL[ks][f] = (f * 16 + m) * 64 + ((((ks << 2) + g) ^ (m & 7)) * 8);

  f32x4 oA[2][4] = {}, oB[2][4] = {};
  float mA[2] = {-INFINITY, -INFINITY}, mB[2] = {-INFINITY, -INFINITY};
  float lA[2] = {0.f, 0.f}, lB[2] = {0.f, 0.f};

  const int idx0 = (((g & 1) << 5) + m) << 2;
  const int idx1 = idx0 + 64;
  const bool hi = (g >= 2);
  int qrelA = qA0 + m - 4 * g;
  int qrelB = qB0 + m - 4 * g;

  auto STAGE = [&](int c, int t) {
    const int kb = t << 6;
#pragma unroll
    for (int i = 0; i < 2; ++i) {
      gld_lds16(K + qkbase + (size_t)(kb + srowS[i]) * Dv + scolS[i],
                &ldsK[c][(i * 4 + wave) * 512]);
      gld_lds16(Vt + vtbase + (size_t)srowS[i] * Sv + kb + scolS[i],
                &ldsV[c][(i * 4 + wave) * 512]);
    }
  };

  STAGE(0, 0);
  STAGE(1, 1);          // ntBmax >= 18 always
  int cur = 0, bs = 2;

  for (int t = 0; t < ntBmax; ++t) {
    if (t + 1 < ntBmax) {
      asm volatile("s_waitcnt vmcnt(4)" ::: "memory");
    } else {
      asm volatile("s_waitcnt vmcnt(0)" ::: "memory");
    }
    __builtin_amdgcn_sched_barrier(0);
    __builtin_amdgcn_s_barrier();      // raw barrier: no vmcnt drain (T4)
    if (t + 2 < ntBmax) STAGE(bs, t + 2);

    if (t < ntB) {
      const bool actA = (t < ntA);
      f32x4 sAacc[2][4], sBacc[2][4];
      short8 kfr[4];
#pragma unroll
      for (int kf = 0; kf < 4; ++kf)
        kfr[kf] = *reinterpret_cast<const short8*>(&ldsK[cur][offL[0][kf]]);
      __builtin_amdgcn_s_setprio(1);
#pragma unroll
      for (int qf = 0; qf < 2; ++qf)
#pragma unroll
        for (int kf = 0; kf < 4; ++kf)
          sBacc[qf][kf] = __builtin_amdgcn_mfma_f32_16x16x32_bf16(kfr[kf], qB[qf][0], zf, 0, 0, 0);
      if (actA)
#pragma unroll
        for (int qf = 0; qf < 2; ++qf)
#pragma unroll
          for (int kf = 0; kf < 4; ++kf)
            sAacc[qf][kf] = __builtin_amdgcn_mfma_f32_16x16x32_bf16(kfr[kf], qA[qf][0], zf, 0, 0, 0);
      __builtin_amdgcn_s_setprio(0);
#pragma unroll
      for (int kf = 0; kf < 4; ++kf)
        kfr[kf] = *reinterpret_cast<const short8*>(&ldsK[cur][offL[1][kf]]);
      __builtin_amdgcn_s_setprio(1);
#pragma unroll
      for (int qf = 0; qf < 2; ++qf)
#pragma unroll
        for (int kf = 0; kf < 4; ++kf)
          sBacc[qf][kf] = __builtin_amdgcn_mfma_f32_16x16x32_bf16(kfr[kf], qB[qf][1], sBacc[qf][kf], 0, 0, 0);
      if (actA)
#pragma unroll
        for (int qf = 0; qf < 2; ++qf)
#pragma unroll
          for (int kf = 0; kf < 4; ++kf)
            sAacc[qf][kf] = __builtin_amdgcn_mfma_f32_16x16x32_bf16(kfr[kf], qA[qf][1], sAacc[qf][kf], 0, 0, 0);
      __builtin_amdgcn_s_setprio(0);

      short8 vfr[2][4];
#pragma unroll
      for (int ks = 0; ks < 2; ++ks)
#pragma unroll
        for (int dc = 0; dc < 4; ++dc)
          vfr[ks][dc] = *reinterpret_cast<const short8*>(&ldsV[cur][offL[ks][dc]]);

      unsigned int pkB[2][4][2], pkA[2][4][2];
      if (t == ntB - 1) softmax_strip<true >(sBacc, qrelB, mB, lB, oB, pkB);
      else              softmax_strip<false>(sBacc, qrelB, mB, lB, oB, pkB);
      if (actA) {
        if (t == ntA - 1) softmax_strip<true >(sAacc, qrelA, mA, lA, oA, pkA);
        else              softmax_strip<false>(sAacc, qrelA, mA, lA, oA, pkA);
      }
      pv_strip(vfr, pkB, oB, idx0, idx1, hi);
      if (actA) pv_strip(vfr, pkA, oA, idx0, idx1, hi);

      qrelA -= 64; qrelB -= 64;
    }

    cur = (cur == 2) ? 0 : cur + 1;
    bs = (bs == 2) ? 0 : bs + 1;
  }

#pragma unroll
  for (int qf = 0; qf < 2; ++qf) {
    float rnA = 1.0f / lA[qf];
    float rnB = 1.0f / lB[qf];
    size_t rowA = (size_t)(qA0 + qf * 16 + m);
    size_t rowB = (size_t)(qB0 + qf * 16 + m);
#pragma unroll
    for (int dc = 0; dc < 4; ++dc) {
      ushort4 ov;
      ov.x = f2bf(oA[qf][dc][0] * rnA);
      ov.y = f2bf(oA[qf][dc][1] * rnA);
      ov.z = f2bf(oA[qf][dc][2] * rnA);
      ov.w = f2bf(oA[qf][dc][3] * rnA);
      *reinterpret_cast<ushort4*>(O + qkbase + rowA * Dv + dc * 16 + 4 * g) = ov;
      ov.x = f2bf(oB[qf][dc][0] * rnB);
      ov.y = f2bf(oB[qf][dc][1] * rnB);
      ov.z = f2bf(oB[qf][dc][2] * rnB);
      ov.w = f2bf(oB[qf][dc][3] * rnB);
      *reinterpret_cast<ushort4*>(O + qkbase + rowB * Dv + dc * 16 + 4 * g) = ov;
    }
  }
}

// ---------------- launcher ----------------
extern "C" void kernel_launch(void* const* d_in, const int* in_sizes, int n_in,
                              void* d_out, int out_size, void* d_ws, size_t ws_size,
                              hipStream_t stream) {
  const float* x   = (const float*)d_in[0];
  const int*   pos = (const int*)d_in[1];
  const float* wq  = (const float*)d_in[2];
  const float* wk  = (const float*)d_in[3];
  const float* wv  = (const float*)d_in[4];
  const float* wo  = (const float*)d_in[5];
  float* out = (float*)d_out;

  char* w = (char*)d_ws;
  unsigned short* xb    = (unsigned short*)(w);               // 16 MB: x bf16, later attn out
  unsigned short* wqkvb = (unsigned short*)(w + (16u << 20)); // 6 MB contiguous [3072][1024]
  unsigned short* wob   = (unsigned short*)(w + (22u << 20)); // 2 MB
  unsigned short* Qp    = (unsigned short*)(w + (24u << 20)); // 16 MB
  unsigned short* Kp    = (unsigned short*)(w + (40u << 20)); // 16 MB
  unsigned short* Vt    = (unsigned short*)(w + (56u << 20)); // 16 MB
  float*          tab   = (float*)(w + (72u << 20));          // 512 KB

  prep_all<<<12544, 256, 0, stream>>>(x, wq, wk, wv, wo, pos, xb, wqkvb, wob, tab);

  gemm_qkv<<<dim3(3 * Dv / 128, Mv / 128), 256, 0, stream>>>(xb, wqkvb, Qp, Kp, Vt, tab);

  attn_mfma<<<512, 256, 0, stream>>>(Qp, Kp, Vt, xb);

  gemm_bt_128<float><<<dim3(Dv / 128, Mv / 128), 256, 0, stream>>>(xb, wob, out, Mv, Dv, Dv);
}